// Round 8
// baseline (118.252 us; speedup 1.0000x reference)
//
#include <hip/hip_runtime.h>
#include <math.h>

#define N_NODES 100000
#define E_EDGES 800000
#define NT 16                 // nodes per MFMA tile
#define NTILES (N_NODES / NT) // 6250
#define NPAIR (NTILES / 2)    // 3125 (one wave handles 2 tiles = 32 nodes)
#define OFF_MU 6400000L
#define OFF_LV 8000000L

typedef __attribute__((ext_vector_type(8))) short short8;
typedef __attribute__((ext_vector_type(4))) float f32x4;
typedef __attribute__((ext_vector_type(4))) float float4v;

// packed-weight fragment regions (units: shorts; each frag = 64 lanes * 8 = 512)
#define SW_AGG 0
#define SW_FUS 8192
#define SW_W1  24576
#define SW_W2  32768
#define SW_W3  36864
#define SW_W4  40960
#define SW_TOT 49152          // 96 KB of shorts

#define PW_OFF (1 << 20)      // packed weights live at ws + 1 MB

__global__ void build_row_start(const int* __restrict__ edge_dst,
                                int* __restrict__ row_start) {
    int e = blockIdx.x * blockDim.x + threadIdx.x;
    if (e >= E_EDGES) return;
    int d = edge_dst[e];
    int dprev = (e == 0) ? -1 : edge_dst[e - 1];
    for (int n = dprev + 1; n <= d; ++n) row_start[n] = e;
    if (e == E_EDGES - 1) {
        for (int n = d + 1; n <= N_NODES; ++n) row_start[n] = E_EDGES;
    }
}

__device__ __forceinline__ unsigned short f2bf(float f) {
    unsigned u = __float_as_uint(f);
    unsigned r = u + 0x7FFFu + ((u >> 16) & 1u);
    return (unsigned short)(r >> 16);
}
__device__ __forceinline__ float bf2f(unsigned short h) {
    return __uint_as_float(((unsigned)h) << 16);
}
__device__ __forceinline__ void split8(const float* v, short8& hi, short8& lo) {
    #pragma unroll
    for (int i = 0; i < 8; ++i) {
        unsigned short h = f2bf(v[i]);
        hi[i] = (short)h;
        lo[i] = (short)f2bf(v[i] - bf2f(h));
    }
}

// XOR-swizzled activation tile address (16 rows x 64 f32 per tile)
__device__ __forceinline__ int actaddr(int row, int col) {
    return row * 64 + ((((col >> 2)) ^ (row & 15)) << 2) + (col & 3);
}

// pack one weight matrix into hi/lo bf16 B-fragment layout (dst in global ws)
__device__ void stage_w(const float* __restrict__ W, int Ksrc, int NC,
                        int NKT, int NJT_local, int jt_off, int NF_tot,
                        int rb, short* sw, int tid) {
    const int tot = NJT_local * NKT * 64;
    for (int s = tid; s < tot; s += 512) {
        int f = s >> 6, l = s & 63;
        int jtl = f / NKT, kt = f - jtl * NKT;
        int col = jtl * 16 + (l & 15);
        int k0 = kt * 32 + ((l >> 4) << 3);
        float v[8];
        #pragma unroll
        for (int i = 0; i < 8; ++i)
            v[i] = (k0 + i < Ksrc) ? W[(k0 + i) * NC + col] : 0.0f;
        short8 hi, lo; split8(v, hi, lo);
        int fg = (jt_off + jtl) * NKT + kt;
        *(short8*)&sw[rb + fg * 512 + l * 8] = hi;
        *(short8*)&sw[rb + (NF_tot + fg) * 512 + l * 8] = lo;
    }
}

__global__ __launch_bounds__(512) void pack_weights(
    const float* __restrict__ W_agg, const float* __restrict__ W_fus,
    const float* __restrict__ W1,  const float* __restrict__ W21,
    const float* __restrict__ W22, const float* __restrict__ W3,
    const float* __restrict__ W4, short* __restrict__ gw) {
    const int tid = threadIdx.x;
    switch (blockIdx.x) {
        case 0: stage_w(W_agg, 64, 64, 2, 4, 0,  8, SW_AGG, gw, tid); break;
        case 1: stage_w(W_fus, 128, 64, 4, 4, 0, 16, SW_FUS, gw, tid); break;
        case 2: stage_w(W1,   64, 64, 2, 4, 0,  8, SW_W1,  gw, tid); break;
        case 3: stage_w(W21,  64, 16, 2, 1, 0,  4, SW_W2,  gw, tid); break;
        case 4: stage_w(W22,  64, 16, 2, 1, 1,  4, SW_W2,  gw, tid); break;
        case 5: stage_w(W3,   16, 64, 1, 4, 0,  4, SW_W3,  gw, tid); break;
        case 6: stage_w(W4,   64, 64, 2, 4, 0,  8, SW_W4,  gw, tid); break;
    }
}

// build A-frags (kt=0,1) for rows base..base+15 of a row-major [*,64] matrix
__device__ __forceinline__ void frags_from_global(const float* __restrict__ rowmat,
                                                  long base, int lane,
                                                  short8* hi, short8* lo) {
    const int row = lane & 15, ko = (lane >> 4) * 8;
    const float* r = rowmat + (base + row) * 64;
    float v[8];
    *(float4v*)&v[0] = *(const float4v*)&r[ko];
    *(float4v*)&v[4] = *(const float4v*)&r[ko + 4];
    split8(v, hi[0], lo[0]);
    *(float4v*)&v[0] = *(const float4v*)&r[32 + ko];
    *(float4v*)&v[4] = *(const float4v*)&r[32 + ko + 4];
    split8(v, hi[1], lo[1]);
}

template<int NKT>
__device__ __forceinline__ void frags_from_act(const float* actw, int lane,
                                               short8* hi, short8* lo) {
    const int row = lane & 15, ko = (lane >> 4) * 8;
    #pragma unroll
    for (int kt = 0; kt < NKT; ++kt) {
        float v[8];
        *(float4v*)&v[0] = *(const float4v*)&actw[actaddr(row, kt * 32 + ko)];
        *(float4v*)&v[4] = *(const float4v*)&actw[actaddr(row, kt * 32 + ko + 4)];
        split8(v, hi[kt], lo[kt]);
    }
}

// dual-tile GEMM: B-frags loaded ONCE from global, used by both tiles
template<int NJT, int NKT>
__device__ __forceinline__ void gemm2(const short8* a0h, const short8* a0l,
                                      const short8* a1h, const short8* a1l,
                                      const short* __restrict__ sw, int rb,
                                      const float* bj, f32x4* c0, f32x4* c1, int lane) {
    #pragma unroll
    for (int jt = 0; jt < NJT; ++jt) {
        f32x4 acc0 = { bj[jt], bj[jt], bj[jt], bj[jt] };
        f32x4 acc1 = acc0;
        #pragma unroll
        for (int kt = 0; kt < NKT; ++kt) {
            const short8 bhi = *(const short8*)&sw[rb + (jt * NKT + kt) * 512 + lane * 8];
            const short8 blo = *(const short8*)&sw[rb + (NJT * NKT + jt * NKT + kt) * 512 + lane * 8];
            acc0 = __builtin_amdgcn_mfma_f32_16x16x32_bf16(a0h[kt], bhi, acc0, 0, 0, 0);
            acc1 = __builtin_amdgcn_mfma_f32_16x16x32_bf16(a1h[kt], bhi, acc1, 0, 0, 0);
            acc0 = __builtin_amdgcn_mfma_f32_16x16x32_bf16(a0l[kt], bhi, acc0, 0, 0, 0);
            acc1 = __builtin_amdgcn_mfma_f32_16x16x32_bf16(a1l[kt], bhi, acc1, 0, 0, 0);
            acc0 = __builtin_amdgcn_mfma_f32_16x16x32_bf16(a0h[kt], blo, acc0, 0, 0, 0);
            acc1 = __builtin_amdgcn_mfma_f32_16x16x32_bf16(a1h[kt], blo, acc1, 0, 0, 0);
        }
        c0[jt] = acc0; c1[jt] = acc1;
    }
}

__device__ __forceinline__ void write_act(float* actw, const f32x4* c, int lane) {
    const int g = lane >> 4, col0 = lane & 15;
    #pragma unroll
    for (int jt = 0; jt < 4; ++jt)
        #pragma unroll
        for (int r = 0; r < 4; ++r)
            actw[actaddr(g * 4 + r, jt * 16 + col0)] = fmaxf(c[jt][r], 0.0f);
}

__device__ __forceinline__ float tree16(const float* v) {
    float a0 = (v[0] + v[1]) + (v[2] + v[3]);
    float a1 = (v[4] + v[5]) + (v[6] + v[7]);
    float a2 = (v[8] + v[9]) + (v[10] + v[11]);
    float a3 = (v[12] + v[13]) + (v[14] + v[15]);
    return (a0 + a1) + (a2 + a3);
}

// issue one masked 16-wide batch of x-row loads for edges [e0, min(e1,e0+16))
__device__ __forceinline__ void issue16(float* v, int e0, int e1, int E0,
                                        int iv0, int iv1, int iv2, int iv3, int iv4,
                                        const int* __restrict__ edge_src,
                                        const float* __restrict__ x, int lane) {
    const int te0 = e0 - E0;
    if (te0 + 15 < 320) {
        const int w0 = te0 >> 6;
        int vlo = iv0, vhi = iv1;
        vlo = (w0 == 1) ? iv1 : vlo; vlo = (w0 == 2) ? iv2 : vlo;
        vlo = (w0 == 3) ? iv3 : vlo; vlo = (w0 == 4) ? iv4 : vlo;
        vhi = (w0 == 1) ? iv2 : vhi; vhi = (w0 == 2) ? iv3 : vhi;
        vhi = (w0 >= 3) ? iv4 : vhi;
        #pragma unroll
        for (int i = 0; i < 16; ++i) {
            const int te = te0 + i;
            const int vsel = ((te >> 6) != w0) ? vhi : vlo;
            int ix = __builtin_amdgcn_readlane(vsel, te & 63);
            const bool live = (e0 + i) < e1;
            ix = live ? ix : 0;
            float t = x[(long)ix * 64 + lane];
            v[i] = live ? t : 0.0f;
        }
    } else {
        #pragma unroll
        for (int i = 0; i < 16; ++i) {
            const int ee = e0 + i;
            const bool live = ee < e1;
            const int ec = ee < E_EDGES ? ee : E_EDGES - 1;
            int ix = edge_src[ec];
            ix = live ? ix : 0;
            float t = x[(long)ix * 64 + lane];
            v[i] = live ? t : 0.0f;
        }
    }
}

__global__ __launch_bounds__(256, 3) void vae_top(
    const float* __restrict__ x,
    const int* __restrict__ edge_src,
    const float* __restrict__ eps,
    const float* __restrict__ b_agg, const float* __restrict__ b_fus,
    const float* __restrict__ b1,  const float* __restrict__ b21,
    const float* __restrict__ b22, const float* __restrict__ b3,
    const float* __restrict__ b4,
    const short* __restrict__ gw,
    const int* __restrict__ row_start,
    float* __restrict__ out)
{
    __shared__ __align__(16) float s_act[8 * 1024];   // 4 waves × 2 tiles × 4 KB

    const int tid  = threadIdx.x;
    const int lane = tid & 63;
    const int wid  = tid >> 6;
    const int pair = blockIdx.x * 4 + wid;            // 2 tiles per wave
    if (pair >= NPAIR) return;

    float* act0 = s_act + wid * 2048;
    float* act1 = act0 + 1024;
    const int cj = lane & 15, g = lane >> 4;
    const long base0 = (long)pair * 32;
    const long base1 = base0 + 16;

    // ---- per-lane bias registers ----
    float bja[4], bjf[4], bj1[4], bj2[2], bj3[4], bj4[4];
    #pragma unroll
    for (int jt = 0; jt < 4; ++jt) {
        bja[jt] = b_agg[jt * 16 + cj];
        bjf[jt] = b_fus[jt * 16 + cj];
        bj1[jt] = b1[jt * 16 + cj];
        bj3[jt] = b3[jt * 16 + cj];
        bj4[jt] = b4[jt * 16 + cj];
    }
    bj2[0] = b21[cj];
    bj2[1] = b22[cj];

    // ---- gather: segment mean for 32 nodes, 2-deep software pipeline ----
    {
        const int idx33 = (int)base0 + (lane < 33 ? lane : 32);
        int rsv = row_start[idx33];
        const int E0 = __builtin_amdgcn_readlane(rsv, 0);

        int p;
        p = E0 + lane;        p = p < E_EDGES ? p : E_EDGES - 1; const int iv0 = edge_src[p];
        p = E0 + 64 + lane;   p = p < E_EDGES ? p : E_EDGES - 1; const int iv1 = edge_src[p];
        p = E0 + 128 + lane;  p = p < E_EDGES ? p : E_EDGES - 1; const int iv2 = edge_src[p];
        p = E0 + 192 + lane;  p = p < E_EDGES ? p : E_EDGES - 1; const int iv3 = edge_src[p];
        p = E0 + 256 + lane;  p = p < E_EDGES ? p : E_EDGES - 1; const int iv4 = edge_src[p];

        float va[16], vb[16];
        int e0a = E0;
        int e1a = __builtin_amdgcn_readlane(rsv, 1);
        issue16(va, e0a, e1a, E0, iv0, iv1, iv2, iv3, iv4, edge_src, x, lane);

        for (int n2 = 0; n2 < 16; ++n2) {
            const int nB = 2 * n2 + 1;
            const int e0b = __builtin_amdgcn_readlane(rsv, nB);
            const int e1b = __builtin_amdgcn_readlane(rsv, nB + 1);
            issue16(vb, e0b, e1b, E0, iv0, iv1, iv2, iv3, iv4, edge_src, x, lane);

            // consume node 2*n2 (va)
            {
                float sum = tree16(va);
                for (int e = e0a + 16; e < e1a; ++e)          // rare (deg>16)
                    sum += x[(long)edge_src[e] * 64 + lane];
                const int nA = 2 * n2;
                float* actn = (nA < 16) ? act0 : act1;
                actn[actaddr(nA & 15, lane)] = sum / fmaxf((float)(e1a - e0a), 1.0f);
            }
            // refill va with node 2*n2+2
            if (n2 < 15) {
                e0a = __builtin_amdgcn_readlane(rsv, 2 * n2 + 2);
                e1a = __builtin_amdgcn_readlane(rsv, 2 * n2 + 3);
                issue16(va, e0a, e1a, E0, iv0, iv1, iv2, iv3, iv4, edge_src, x, lane);
            }
            // consume node 2*n2+1 (vb)
            {
                float sum = tree16(vb);
                for (int e = e0b + 16; e < e1b; ++e)          // rare
                    sum += x[(long)edge_src[e] * 64 + lane];
                float* actn = (nB < 16) ? act0 : act1;
                actn[actaddr(nB & 15, lane)] = sum / fmaxf((float)(e1b - e0b), 1.0f);
            }
        }
    }

    short8 ah0[4], al0[4], ah1[4], al1[4];
    f32x4 c40[4], c41[4];

    // ---- ne = relu(avg @ W_agg + b_agg) ----
    frags_from_act<2>(act0, lane, ah0, al0);
    frags_from_act<2>(act1, lane, ah1, al1);
    gemm2<4, 2>(ah0, al0, ah1, al1, gw, SW_AGG, bja, c40, c41, lane);
    write_act(act0, c40, lane);
    write_act(act1, c41, lane);

    // ---- xf = relu([x, ne] @ W_fus + b_fus) ----
    frags_from_global(x, base0, lane, ah0, al0);
    frags_from_act<2>(act0, lane, ah0 + 2, al0 + 2);
    frags_from_global(x, base1, lane, ah1, al1);
    frags_from_act<2>(act1, lane, ah1 + 2, al1 + 2);
    gemm2<4, 4>(ah0, al0, ah1, al1, gw, SW_FUS, bjf, c40, c41, lane);
    write_act(act0, c40, lane);
    write_act(act1, c41, lane);

    // ---- h1 = relu(xf @ W1 + b1) ----
    frags_from_act<2>(act0, lane, ah0, al0);
    frags_from_act<2>(act1, lane, ah1, al1);
    gemm2<4, 2>(ah0, al0, ah1, al1, gw, SW_W1, bj1, c40, c41, lane);
    write_act(act0, c40, lane);
    write_act(act1, c41, lane);

    // ---- mu / logvar (combined 64x32 GEMM: jt0=mu, jt1=lv) ----
    frags_from_act<2>(act0, lane, ah0, al0);
    frags_from_act<2>(act1, lane, ah1, al1);
    f32x4 c20[2], c21[2];
    gemm2<2, 2>(ah0, al0, ah1, al1, gw, SW_W2, bj2, c20, c21, lane);

    // ---- store mu/lv; z = mu + eps*exp(0.5*lv) ----
    float z40[4], z41[4];
    #pragma unroll
    for (int r = 0; r < 4; ++r) {
        const long n0 = base0 + g * 4 + r;
        out[OFF_MU + n0 * 16 + cj] = c20[0][r];
        out[OFF_LV + n0 * 16 + cj] = c20[1][r];
        z40[r] = c20[0][r] + eps[n0 * 16 + cj] * __expf(0.5f * c20[1][r]);
        const long n1 = base1 + g * 4 + r;
        out[OFF_MU + n1 * 16 + cj] = c21[0][r];
        out[OFF_LV + n1 * 16 + cj] = c21[1][r];
        z41[r] = c21[0][r] + eps[n1 * 16 + cj] * __expf(0.5f * c21[1][r]);
    }

    // ---- h3 = relu(z @ W3 + b3), K padded to 32 ----
    #pragma unroll
    for (int r = 0; r < 4; ++r) {
        act0[actaddr(g * 4 + r, cj)] = z40[r];
        act1[actaddr(g * 4 + r, cj)] = z41[r];
    }
    {
        short8 zh0 = {0,0,0,0,0,0,0,0}, zl0 = {0,0,0,0,0,0,0,0};
        short8 zh1 = {0,0,0,0,0,0,0,0}, zl1 = {0,0,0,0,0,0,0,0};
        if (lane < 32) {
            float v[8];
            const int row = lane & 15, ko = (lane >> 4) * 8;  // 0 or 8
            *(float4v*)&v[0] = *(const float4v*)&act0[actaddr(row, ko)];
            *(float4v*)&v[4] = *(const float4v*)&act0[actaddr(row, ko + 4)];
            split8(v, zh0, zl0);
            *(float4v*)&v[0] = *(const float4v*)&act1[actaddr(row, ko)];
            *(float4v*)&v[4] = *(const float4v*)&act1[actaddr(row, ko + 4)];
            split8(v, zh1, zl1);
        }
        gemm2<4, 1>(&zh0, &zl0, &zh1, &zl1, gw, SW_W3, bj3, c40, c41, lane);
    }
    write_act(act0, c40, lane);
    write_act(act1, c41, lane);

    // ---- recon = sigmoid(h3 @ W4 + b4) ----
    frags_from_act<2>(act0, lane, ah0, al0);
    frags_from_act<2>(act1, lane, ah1, al1);
    gemm2<4, 2>(ah0, al0, ah1, al1, gw, SW_W4, bj4, c40, c41, lane);
    #pragma unroll
    for (int jt = 0; jt < 4; ++jt)
        #pragma unroll
        for (int r = 0; r < 4; ++r) {
            const float s0 = 1.0f / (1.0f + __expf(-c40[jt][r]));
            out[(base0 + g * 4 + r) * 64 + jt * 16 + cj] = s0;
            const float s1 = 1.0f / (1.0f + __expf(-c41[jt][r]));
            out[(base1 + g * 4 + r) * 64 + jt * 16 + cj] = s1;
        }
}

extern "C" void kernel_launch(void* const* d_in, const int* in_sizes, int n_in,
                              void* d_out, int out_size, void* d_ws, size_t ws_size,
                              hipStream_t stream) {
    const float* x        = (const float*)d_in[0];
    const int*   edge_src = (const int*)  d_in[1];
    const int*   edge_dst = (const int*)  d_in[2];
    const float* eps      = (const float*)d_in[3];
    const float* W_agg    = (const float*)d_in[4];
    const float* b_agg    = (const float*)d_in[5];
    const float* W_fus    = (const float*)d_in[6];
    const float* b_fus    = (const float*)d_in[7];
    const float* W1       = (const float*)d_in[8];
    const float* b1       = (const float*)d_in[9];
    const float* W21      = (const float*)d_in[10];
    const float* b21      = (const float*)d_in[11];
    const float* W22      = (const float*)d_in[12];
    const float* b22      = (const float*)d_in[13];
    const float* W3       = (const float*)d_in[14];
    const float* b3       = (const float*)d_in[15];
    const float* W4       = (const float*)d_in[16];
    const float* b4       = (const float*)d_in[17];
    float* out = (float*)d_out;

    int*   row_start = (int*)d_ws;
    short* gw        = (short*)((char*)d_ws + PW_OFF);

    build_row_start<<<(E_EDGES + 255) / 256, 256, 0, stream>>>(edge_dst, row_start);
    pack_weights<<<7, 512, 0, stream>>>(W_agg, W_fus, W1, W21, W22, W3, W4, gw);
    vae_top<<<(NPAIR + 3) / 4, 256, 0, stream>>>(x, edge_src, eps,
                                                 b_agg, b_fus, b1, b21, b22, b3, b4,
                                                 gw, row_start, out);
}

// Round 9
// 105.766 us; speedup vs baseline: 1.1181x; 1.1181x over previous
//
#include <hip/hip_runtime.h>
#include <math.h>

#define N_NODES 100000
#define E_EDGES 800000
#define NT 16                 // nodes per MFMA tile
#define NTILES (N_NODES / NT) // 6250 (one block per tile, 4 waves split the jt cols)
#define OFF_MU 6400000L
#define OFF_LV 8000000L

typedef __attribute__((ext_vector_type(8))) short short8;
typedef __attribute__((ext_vector_type(4))) float f32x4;
typedef __attribute__((ext_vector_type(4))) float float4v;

// packed-weight fragment regions (units: shorts; each frag = 64 lanes * 8 = 512)
#define SW_AGG 0
#define SW_FUS 8192
#define SW_W1  24576
#define SW_W2  32768
#define SW_W3  36864
#define SW_W4  40960
#define SW_TOT 49152          // 96 KB of shorts

#define PW_OFF (1 << 20)      // packed weights live at ws + 1 MB

__global__ void build_row_start(const int* __restrict__ edge_dst,
                                int* __restrict__ row_start) {
    int e = blockIdx.x * blockDim.x + threadIdx.x;
    if (e >= E_EDGES) return;
    int d = edge_dst[e];
    int dprev = (e == 0) ? -1 : edge_dst[e - 1];
    for (int n = dprev + 1; n <= d; ++n) row_start[n] = e;
    if (e == E_EDGES - 1) {
        for (int n = d + 1; n <= N_NODES; ++n) row_start[n] = E_EDGES;
    }
}

__device__ __forceinline__ unsigned short f2bf(float f) {
    unsigned u = __float_as_uint(f);
    unsigned r = u + 0x7FFFu + ((u >> 16) & 1u);
    return (unsigned short)(r >> 16);
}
__device__ __forceinline__ float bf2f(unsigned short h) {
    return __uint_as_float(((unsigned)h) << 16);
}
__device__ __forceinline__ void split8(const float* v, short8& hi, short8& lo) {
    #pragma unroll
    for (int i = 0; i < 8; ++i) {
        unsigned short h = f2bf(v[i]);
        hi[i] = (short)h;
        lo[i] = (short)f2bf(v[i] - bf2f(h));
    }
}

// XOR-swizzled activation tile address (16 rows x 64 f32)
__device__ __forceinline__ int actaddr(int row, int col) {
    return row * 64 + ((((col >> 2)) ^ (row & 15)) << 2) + (col & 3);
}

// pack one weight matrix into hi/lo bf16 B-fragment layout (dst in global ws)
__device__ void stage_w(const float* __restrict__ W, int Ksrc, int NC,
                        int NKT, int NJT_local, int jt_off, int NF_tot,
                        int rb, short* sw, int tid) {
    const int tot = NJT_local * NKT * 64;
    for (int s = tid; s < tot; s += 512) {
        int f = s >> 6, l = s & 63;
        int jtl = f / NKT, kt = f - jtl * NKT;
        int col = jtl * 16 + (l & 15);
        int k0 = kt * 32 + ((l >> 4) << 3);
        float v[8];
        #pragma unroll
        for (int i = 0; i < 8; ++i)
            v[i] = (k0 + i < Ksrc) ? W[(k0 + i) * NC + col] : 0.0f;
        short8 hi, lo; split8(v, hi, lo);
        int fg = (jt_off + jtl) * NKT + kt;
        *(short8*)&sw[rb + fg * 512 + l * 8] = hi;
        *(short8*)&sw[rb + (NF_tot + fg) * 512 + l * 8] = lo;
    }
}

__global__ __launch_bounds__(512) void pack_weights(
    const float* __restrict__ W_agg, const float* __restrict__ W_fus,
    const float* __restrict__ W1,  const float* __restrict__ W21,
    const float* __restrict__ W22, const float* __restrict__ W3,
    const float* __restrict__ W4, short* __restrict__ gw) {
    const int tid = threadIdx.x;
    switch (blockIdx.x) {
        case 0: stage_w(W_agg, 64, 64, 2, 4, 0,  8, SW_AGG, gw, tid); break;
        case 1: stage_w(W_fus, 128, 64, 4, 4, 0, 16, SW_FUS, gw, tid); break;
        case 2: stage_w(W1,   64, 64, 2, 4, 0,  8, SW_W1,  gw, tid); break;
        case 3: stage_w(W21,  64, 16, 2, 1, 0,  4, SW_W2,  gw, tid); break;
        case 4: stage_w(W22,  64, 16, 2, 1, 1,  4, SW_W2,  gw, tid); break;
        case 5: stage_w(W3,   16, 64, 1, 4, 0,  4, SW_W3,  gw, tid); break;
        case 6: stage_w(W4,   64, 64, 2, 4, 0,  8, SW_W4,  gw, tid); break;
    }
}

// build A-frags (kt=0,1) for rows base..base+15 of a row-major [*,64] matrix
__device__ __forceinline__ void frags_from_global(const float* __restrict__ rowmat,
                                                  long base, int lane,
                                                  short8* hi, short8* lo) {
    const int row = lane & 15, ko = (lane >> 4) * 8;
    const float* r = rowmat + (base + row) * 64;
    float v[8];
    *(float4v*)&v[0] = *(const float4v*)&r[ko];
    *(float4v*)&v[4] = *(const float4v*)&r[ko + 4];
    split8(v, hi[0], lo[0]);
    *(float4v*)&v[0] = *(const float4v*)&r[32 + ko];
    *(float4v*)&v[4] = *(const float4v*)&r[32 + ko + 4];
    split8(v, hi[1], lo[1]);
}

template<int NKT>
__device__ __forceinline__ void frags_from_act(const float* actw, int lane,
                                               short8* hi, short8* lo) {
    const int row = lane & 15, ko = (lane >> 4) * 8;
    #pragma unroll
    for (int kt = 0; kt < NKT; ++kt) {
        float v[8];
        *(float4v*)&v[0] = *(const float4v*)&actw[actaddr(row, kt * 32 + ko)];
        *(float4v*)&v[4] = *(const float4v*)&actw[actaddr(row, kt * 32 + ko + 4)];
        split8(v, hi[kt], lo[kt]);
    }
}

// one jt-column-slab GEMM (16 rows x 16 cols), B-frags from global packed weights
template<int NKT>
__device__ __forceinline__ f32x4 gemm_one(const short8* ah, const short8* al,
                                          const short* __restrict__ sw, int rb,
                                          int jt, int NF, float bias, int lane) {
    f32x4 acc = { bias, bias, bias, bias };
    #pragma unroll
    for (int kt = 0; kt < NKT; ++kt) {
        const short8 bhi = *(const short8*)&sw[rb + (jt * NKT + kt) * 512 + lane * 8];
        const short8 blo = *(const short8*)&sw[rb + (NF + jt * NKT + kt) * 512 + lane * 8];
        acc = __builtin_amdgcn_mfma_f32_16x16x32_bf16(ah[kt], bhi, acc, 0, 0, 0);
        acc = __builtin_amdgcn_mfma_f32_16x16x32_bf16(al[kt], bhi, acc, 0, 0, 0);
        acc = __builtin_amdgcn_mfma_f32_16x16x32_bf16(ah[kt], blo, acc, 0, 0, 0);
    }
    return acc;
}

__device__ __forceinline__ void write_slab(float* actw, f32x4 c, int jt, int lane) {
    const int g = lane >> 4, cj = lane & 15;
    #pragma unroll
    for (int r = 0; r < 4; ++r)
        actw[actaddr(g * 4 + r, jt * 16 + cj)] = fmaxf(c[r], 0.0f);
}

__device__ __forceinline__ float tree16(const float* v) {
    float a0 = (v[0] + v[1]) + (v[2] + v[3]);
    float a1 = (v[4] + v[5]) + (v[6] + v[7]);
    float a2 = (v[8] + v[9]) + (v[10] + v[11]);
    float a3 = (v[12] + v[13]) + (v[14] + v[15]);
    return (a0 + a1) + (a2 + a3);
}

// 1 block = 1 tile (16 nodes); 4 waves split the 4 jt column slabs.
__global__ __launch_bounds__(256, 8) void vae_top(
    const float* __restrict__ x,
    const int* __restrict__ edge_src,
    const float* __restrict__ eps,
    const float* __restrict__ b_agg, const float* __restrict__ b_fus,
    const float* __restrict__ b1,  const float* __restrict__ b21,
    const float* __restrict__ b22, const float* __restrict__ b3,
    const float* __restrict__ b4,
    const short* __restrict__ gw,
    const int* __restrict__ row_start,
    float* __restrict__ out)
{
    __shared__ __align__(16) float sA[1024];   // 16x64 act tile (ping)
    __shared__ __align__(16) float sB[1024];   // (pong)

    const int tid  = threadIdx.x;
    const int lane = tid & 63;
    const int wid  = tid >> 6;       // wave id == jt slab
    const long base = (long)blockIdx.x * NT;
    const int cj = lane & 15, g = lane >> 4;

    // per-wave biases for own jt slab
    const float bja = b_agg[wid * 16 + cj];
    const float bjf = b_fus[wid * 16 + cj];
    const float bj1 = b1[wid * 16 + cj];
    const float bj3 = b3[wid * 16 + cj];
    const float bj4 = b4[wid * 16 + cj];

    // ---- gather: each wave does 4 nodes (one masked 16-wide batch each) ----
    {
        const int rsv = row_start[(int)base + (lane < 17 ? lane : 16)];
        const int W0 = __builtin_amdgcn_readlane(rsv, wid * 4);
        int p0 = W0 + lane;      p0 = p0 < E_EDGES ? p0 : E_EDGES - 1;
        int p1 = W0 + 64 + lane; p1 = p1 < E_EDGES ? p1 : E_EDGES - 1;
        const int iv0 = edge_src[p0];
        const int iv1 = edge_src[p1];

        #pragma unroll
        for (int q = 0; q < 4; ++q) {
            const int node = wid * 4 + q;
            const int e0 = __builtin_amdgcn_readlane(rsv, node);
            const int e1 = __builtin_amdgcn_readlane(rsv, node + 1);
            float v[16];
            const int te0 = e0 - W0;
            if (te0 + 15 < 128) {
                #pragma unroll
                for (int i = 0; i < 16; ++i) {
                    const int te = te0 + i;
                    const int vsel = (te & 64) ? iv1 : iv0;
                    int ix = __builtin_amdgcn_readlane(vsel, te & 63);
                    const bool live = (e0 + i) < e1;
                    ix = live ? ix : 0;
                    float tv = x[(long)ix * 64 + lane];
                    v[i] = live ? tv : 0.0f;
                }
            } else {
                #pragma unroll
                for (int i = 0; i < 16; ++i) {
                    const int ee = e0 + i;
                    const bool live = ee < e1;
                    const int ec = ee < E_EDGES ? ee : E_EDGES - 1;
                    int ix = edge_src[ec];
                    ix = live ? ix : 0;
                    float tv = x[(long)ix * 64 + lane];
                    v[i] = live ? tv : 0.0f;
                }
            }
            float sum = tree16(v);
            for (int e = e0 + 16; e < e1; ++e)          // rare (deg>16)
                sum += x[(long)edge_src[e] * 64 + lane];
            sA[actaddr(node, lane)] = sum / fmaxf((float)(e1 - e0), 1.0f);
        }
    }
    __syncthreads();

    short8 ah[4], al[4];
    f32x4 c;

    // ---- ne = relu(avg @ W_agg + b_agg): sA -> sB ----
    frags_from_act<2>(sA, lane, ah, al);
    c = gemm_one<2>(ah, al, gw, SW_AGG, wid, 8, bja, lane);
    write_slab(sB, c, wid, lane);
    __syncthreads();

    // ---- xf = relu([x, ne] @ W_fus + b_fus): x + sB -> sA ----
    frags_from_global(x, base, lane, ah, al);        // kt 0,1 (x)
    frags_from_act<2>(sB, lane, ah + 2, al + 2);     // kt 2,3 (ne)
    c = gemm_one<4>(ah, al, gw, SW_FUS, wid, 16, bjf, lane);
    write_slab(sA, c, wid, lane);
    __syncthreads();

    // ---- h1 = relu(xf @ W1 + b1): sA -> sB ----
    frags_from_act<2>(sA, lane, ah, al);
    c = gemm_one<2>(ah, al, gw, SW_W1, wid, 8, bj1, lane);
    write_slab(sB, c, wid, lane);
    __syncthreads();

    // ---- mu/lv/z (wave 0 only): sB -> z into sA cols 0..15 ----
    if (wid == 0) {
        frags_from_act<2>(sB, lane, ah, al);
        const f32x4 cmu = gemm_one<2>(ah, al, gw, SW_W2, 0, 4, b21[cj], lane);
        const f32x4 clv = gemm_one<2>(ah, al, gw, SW_W2, 1, 4, b22[cj], lane);
        #pragma unroll
        for (int r = 0; r < 4; ++r) {
            const long node = base + g * 4 + r;
            out[OFF_MU + node * 16 + cj] = cmu[r];
            out[OFF_LV + node * 16 + cj] = clv[r];
            const float z = cmu[r] + eps[node * 16 + cj] * __expf(0.5f * clv[r]);
            sA[actaddr(g * 4 + r, cj)] = z;
        }
    }
    __syncthreads();

    // ---- h3 = relu(z @ W3 + b3): sA(z, K padded to 32) -> sB ----
    {
        short8 zh = {0,0,0,0,0,0,0,0}, zl = {0,0,0,0,0,0,0,0};
        if (lane < 32) {
            float v[8];
            const int row = lane & 15, ko = (lane >> 4) * 8;  // 0 or 8
            *(float4v*)&v[0] = *(const float4v*)&sA[actaddr(row, ko)];
            *(float4v*)&v[4] = *(const float4v*)&sA[actaddr(row, ko + 4)];
            split8(v, zh, zl);
        }
        c = gemm_one<1>(&zh, &zl, gw, SW_W3, wid, 4, bj3, lane);
    }
    write_slab(sB, c, wid, lane);
    __syncthreads();

    // ---- recon = sigmoid(h3 @ W4 + b4): sB -> out ----
    frags_from_act<2>(sB, lane, ah, al);
    c = gemm_one<2>(ah, al, gw, SW_W4, wid, 8, bj4, lane);
    #pragma unroll
    for (int r = 0; r < 4; ++r) {
        const float s = 1.0f / (1.0f + __expf(-c[r]));
        out[(base + g * 4 + r) * 64 + wid * 16 + cj] = s;
    }
}

extern "C" void kernel_launch(void* const* d_in, const int* in_sizes, int n_in,
                              void* d_out, int out_size, void* d_ws, size_t ws_size,
                              hipStream_t stream) {
    const float* x        = (const float*)d_in[0];
    const int*   edge_src = (const int*)  d_in[1];
    const int*   edge_dst = (const int*)  d_in[2];
    const float* eps      = (const float*)d_in[3];
    const float* W_agg    = (const float*)d_in[4];
    const float* b_agg    = (const float*)d_in[5];
    const float* W_fus    = (const float*)d_in[6];
    const float* b_fus    = (const float*)d_in[7];
    const float* W1       = (const float*)d_in[8];
    const float* b1       = (const float*)d_in[9];
    const float* W21      = (const float*)d_in[10];
    const float* b21      = (const float*)d_in[11];
    const float* W22      = (const float*)d_in[12];
    const float* b22      = (const float*)d_in[13];
    const float* W3       = (const float*)d_in[14];
    const float* b3       = (const float*)d_in[15];
    const float* W4       = (const float*)d_in[16];
    const float* b4       = (const float*)d_in[17];
    float* out = (float*)d_out;

    int*   row_start = (int*)d_ws;
    short* gw        = (short*)((char*)d_ws + PW_OFF);

    build_row_start<<<(E_EDGES + 255) / 256, 256, 0, stream>>>(edge_dst, row_start);
    pack_weights<<<7, 512, 0, stream>>>(W_agg, W_fus, W1, W21, W22, W3, W4, gw);
    vae_top<<<NTILES, 256, 0, stream>>>(x, edge_src, eps,
                                        b_agg, b_fus, b1, b21, b22, b3, b4,
                                        gw, row_start, out);
}

// Round 10
// 87.791 us; speedup vs baseline: 1.3470x; 1.2047x over previous
//
#include <hip/hip_runtime.h>
#include <math.h>

#define N_NODES 100000
#define E_EDGES 800000
#define NT 16                 // nodes per MFMA tile
#define NTILES (N_NODES / NT) // 6250 (one block per tile, 4 waves split the jt cols)
#define OFF_MU 6400000L
#define OFF_LV 8000000L

typedef __attribute__((ext_vector_type(8))) short short8;
typedef __attribute__((ext_vector_type(4))) float f32x4;
typedef __attribute__((ext_vector_type(4))) float float4v;

// packed-weight fragment regions (units: shorts; each frag = 64 lanes * 8 = 512)
#define SW_AGG 0
#define SW_FUS 8192
#define SW_W1  24576
#define SW_W2  32768
#define SW_W3  36864
#define SW_W4  40960
#define SW_TOT 49152          // 96 KB of shorts

#define PW_OFF (1 << 20)      // packed weights live at ws + 1 MB

__global__ void build_row_start(const int* __restrict__ edge_dst,
                                int* __restrict__ row_start) {
    int e = blockIdx.x * blockDim.x + threadIdx.x;
    if (e >= E_EDGES) return;
    int d = edge_dst[e];
    int dprev = (e == 0) ? -1 : edge_dst[e - 1];
    for (int n = dprev + 1; n <= d; ++n) row_start[n] = e;
    if (e == E_EDGES - 1) {
        for (int n = d + 1; n <= N_NODES; ++n) row_start[n] = E_EDGES;
    }
}

__device__ __forceinline__ unsigned short f2bf(float f) {
    unsigned u = __float_as_uint(f);
    unsigned r = u + 0x7FFFu + ((u >> 16) & 1u);
    return (unsigned short)(r >> 16);
}
__device__ __forceinline__ float bf2f(unsigned short h) {
    return __uint_as_float(((unsigned)h) << 16);
}
__device__ __forceinline__ void split8(const float* v, short8& hi, short8& lo) {
    #pragma unroll
    for (int i = 0; i < 8; ++i) {
        unsigned short h = f2bf(v[i]);
        hi[i] = (short)h;
        lo[i] = (short)f2bf(v[i] - bf2f(h));
    }
}

// XOR-swizzled activation tile address (16 rows x 64 f32)
__device__ __forceinline__ int actaddr(int row, int col) {
    return row * 64 + ((((col >> 2)) ^ (row & 15)) << 2) + (col & 3);
}

// pack one weight matrix into hi/lo bf16 B-fragment layout (dst in global ws)
__device__ void stage_w(const float* __restrict__ W, int Ksrc, int NC,
                        int NKT, int NJT_local, int jt_off, int NF_tot,
                        int rb, short* sw, int tid) {
    const int tot = NJT_local * NKT * 64;
    for (int s = tid; s < tot; s += 512) {
        int f = s >> 6, l = s & 63;
        int jtl = f / NKT, kt = f - jtl * NKT;
        int col = jtl * 16 + (l & 15);
        int k0 = kt * 32 + ((l >> 4) << 3);
        float v[8];
        #pragma unroll
        for (int i = 0; i < 8; ++i)
            v[i] = (k0 + i < Ksrc) ? W[(k0 + i) * NC + col] : 0.0f;
        short8 hi, lo; split8(v, hi, lo);
        int fg = (jt_off + jtl) * NKT + kt;
        *(short8*)&sw[rb + fg * 512 + l * 8] = hi;
        *(short8*)&sw[rb + (NF_tot + fg) * 512 + l * 8] = lo;
    }
}

__global__ __launch_bounds__(512) void pack_weights(
    const float* __restrict__ W_agg, const float* __restrict__ W_fus,
    const float* __restrict__ W1,  const float* __restrict__ W21,
    const float* __restrict__ W22, const float* __restrict__ W3,
    const float* __restrict__ W4, short* __restrict__ gw) {
    const int tid = threadIdx.x;
    switch (blockIdx.x) {
        case 0: stage_w(W_agg, 64, 64, 2, 4, 0,  8, SW_AGG, gw, tid); break;
        case 1: stage_w(W_fus, 128, 64, 4, 4, 0, 16, SW_FUS, gw, tid); break;
        case 2: stage_w(W1,   64, 64, 2, 4, 0,  8, SW_W1,  gw, tid); break;
        case 3: stage_w(W21,  64, 16, 2, 1, 0,  4, SW_W2,  gw, tid); break;
        case 4: stage_w(W22,  64, 16, 2, 1, 1,  4, SW_W2,  gw, tid); break;
        case 5: stage_w(W3,   16, 64, 1, 4, 0,  4, SW_W3,  gw, tid); break;
        case 6: stage_w(W4,   64, 64, 2, 4, 0,  8, SW_W4,  gw, tid); break;
    }
}

// build A-frags (kt=0,1) for rows base..base+15 of a row-major [*,64] matrix
__device__ __forceinline__ void frags_from_global(const float* __restrict__ rowmat,
                                                  long base, int lane,
                                                  short8* hi, short8* lo) {
    const int row = lane & 15, ko = (lane >> 4) * 8;
    const float* r = rowmat + (base + row) * 64;
    float v[8];
    *(float4v*)&v[0] = *(const float4v*)&r[ko];
    *(float4v*)&v[4] = *(const float4v*)&r[ko + 4];
    split8(v, hi[0], lo[0]);
    *(float4v*)&v[0] = *(const float4v*)&r[32 + ko];
    *(float4v*)&v[4] = *(const float4v*)&r[32 + ko + 4];
    split8(v, hi[1], lo[1]);
}

template<int NKT>
__device__ __forceinline__ void frags_from_act(const float* actw, int lane,
                                               short8* hi, short8* lo) {
    const int row = lane & 15, ko = (lane >> 4) * 8;
    #pragma unroll
    for (int kt = 0; kt < NKT; ++kt) {
        float v[8];
        *(float4v*)&v[0] = *(const float4v*)&actw[actaddr(row, kt * 32 + ko)];
        *(float4v*)&v[4] = *(const float4v*)&actw[actaddr(row, kt * 32 + ko + 4)];
        split8(v, hi[kt], lo[kt]);
    }
}

// one jt-column-slab GEMM (16 rows x 16 cols), B-frags from global packed weights
template<int NKT>
__device__ __forceinline__ f32x4 gemm_one(const short8* ah, const short8* al,
                                          const short* __restrict__ sw, int rb,
                                          int jt, int NF, float bias, int lane) {
    f32x4 acc = { bias, bias, bias, bias };
    #pragma unroll
    for (int kt = 0; kt < NKT; ++kt) {
        const short8 bhi = *(const short8*)&sw[rb + (jt * NKT + kt) * 512 + lane * 8];
        const short8 blo = *(const short8*)&sw[rb + (NF + jt * NKT + kt) * 512 + lane * 8];
        acc = __builtin_amdgcn_mfma_f32_16x16x32_bf16(ah[kt], bhi, acc, 0, 0, 0);
        acc = __builtin_amdgcn_mfma_f32_16x16x32_bf16(al[kt], bhi, acc, 0, 0, 0);
        acc = __builtin_amdgcn_mfma_f32_16x16x32_bf16(ah[kt], blo, acc, 0, 0, 0);
    }
    return acc;
}

__device__ __forceinline__ void write_slab(float* actw, f32x4 c, int jt, int lane) {
    const int g = lane >> 4, cj = lane & 15;
    #pragma unroll
    for (int r = 0; r < 4; ++r)
        actw[actaddr(g * 4 + r, jt * 16 + cj)] = fmaxf(c[r], 0.0f);
}

__device__ __forceinline__ float tree16(const float* v) {
    float a0 = (v[0] + v[1]) + (v[2] + v[3]);
    float a1 = (v[4] + v[5]) + (v[6] + v[7]);
    float a2 = (v[8] + v[9]) + (v[10] + v[11]);
    float a3 = (v[12] + v[13]) + (v[14] + v[15]);
    return (a0 + a1) + (a2 + a3);
}

// 1 block = 1 tile (16 nodes); 4 waves split the 4 jt column slabs.
// launch_bounds(256,6): ~85 VGPR cap — enough for the 16-deep gather batch
// (r9's (256,8) forced 32 VGPRs -> scratch spill -> +120MB HBM writes).
__global__ __launch_bounds__(256, 6) void vae_top(
    const float* __restrict__ x,
    const int* __restrict__ edge_src,
    const float* __restrict__ eps,
    const float* __restrict__ b_agg, const float* __restrict__ b_fus,
    const float* __restrict__ b1,  const float* __restrict__ b21,
    const float* __restrict__ b22, const float* __restrict__ b3,
    const float* __restrict__ b4,
    const short* __restrict__ gw,
    const int* __restrict__ row_start,
    float* __restrict__ out)
{
    __shared__ __align__(16) float sA[1024];   // 16x64 act tile (ping)
    __shared__ __align__(16) float sB[1024];   // (pong)

    const int tid  = threadIdx.x;
    const int lane = tid & 63;
    const int wid  = tid >> 6;       // wave id == jt slab
    const long base = (long)blockIdx.x * NT;
    const int cj = lane & 15, g = lane >> 4;

    // per-wave biases for own jt slab
    const float bja = b_agg[wid * 16 + cj];
    const float bjf = b_fus[wid * 16 + cj];
    const float bj1 = b1[wid * 16 + cj];
    const float bj3 = b3[wid * 16 + cj];
    const float bj4 = b4[wid * 16 + cj];

    // ---- gather: each wave does 4 nodes (one masked 16-wide batch each) ----
    {
        const int rsv = row_start[(int)base + (lane < 17 ? lane : 16)];
        const int W0 = __builtin_amdgcn_readlane(rsv, wid * 4);
        int p0 = W0 + lane;      p0 = p0 < E_EDGES ? p0 : E_EDGES - 1;
        int p1 = W0 + 64 + lane; p1 = p1 < E_EDGES ? p1 : E_EDGES - 1;
        const int iv0 = edge_src[p0];
        const int iv1 = edge_src[p1];

        #pragma unroll
        for (int q = 0; q < 4; ++q) {
            const int node = wid * 4 + q;
            const int e0 = __builtin_amdgcn_readlane(rsv, node);
            const int e1 = __builtin_amdgcn_readlane(rsv, node + 1);
            float v[16];
            const int te0 = e0 - W0;
            if (te0 + 15 < 128) {
                #pragma unroll
                for (int i = 0; i < 16; ++i) {
                    const int te = te0 + i;
                    const int vsel = (te & 64) ? iv1 : iv0;
                    int ix = __builtin_amdgcn_readlane(vsel, te & 63);
                    const bool live = (e0 + i) < e1;
                    ix = live ? ix : 0;
                    float tv = x[(long)ix * 64 + lane];
                    v[i] = live ? tv : 0.0f;
                }
            } else {
                #pragma unroll
                for (int i = 0; i < 16; ++i) {
                    const int ee = e0 + i;
                    const bool live = ee < e1;
                    const int ec = ee < E_EDGES ? ee : E_EDGES - 1;
                    int ix = edge_src[ec];
                    ix = live ? ix : 0;
                    float tv = x[(long)ix * 64 + lane];
                    v[i] = live ? tv : 0.0f;
                }
            }
            float sum = tree16(v);
            for (int e = e0 + 16; e < e1; ++e)          // rare (deg>16)
                sum += x[(long)edge_src[e] * 64 + lane];
            sA[actaddr(node, lane)] = sum / fmaxf((float)(e1 - e0), 1.0f);
        }
    }
    __syncthreads();

    short8 ah[4], al[4];
    f32x4 c;

    // ---- ne = relu(avg @ W_agg + b_agg): sA -> sB ----
    frags_from_act<2>(sA, lane, ah, al);
    c = gemm_one<2>(ah, al, gw, SW_AGG, wid, 8, bja, lane);
    write_slab(sB, c, wid, lane);
    __syncthreads();

    // ---- xf = relu([x, ne] @ W_fus + b_fus): x + sB -> sA ----
    frags_from_global(x, base, lane, ah, al);        // kt 0,1 (x)
    frags_from_act<2>(sB, lane, ah + 2, al + 2);     // kt 2,3 (ne)
    c = gemm_one<4>(ah, al, gw, SW_FUS, wid, 16, bjf, lane);
    write_slab(sA, c, wid, lane);
    __syncthreads();

    // ---- h1 = relu(xf @ W1 + b1): sA -> sB ----
    frags_from_act<2>(sA, lane, ah, al);
    c = gemm_one<2>(ah, al, gw, SW_W1, wid, 8, bj1, lane);
    write_slab(sB, c, wid, lane);
    __syncthreads();

    // ---- mu/lv/z (wave 0 only): sB -> z into sA cols 0..15 ----
    if (wid == 0) {
        frags_from_act<2>(sB, lane, ah, al);
        const f32x4 cmu = gemm_one<2>(ah, al, gw, SW_W2, 0, 4, b21[cj], lane);
        const f32x4 clv = gemm_one<2>(ah, al, gw, SW_W2, 1, 4, b22[cj], lane);
        #pragma unroll
        for (int r = 0; r < 4; ++r) {
            const long node = base + g * 4 + r;
            out[OFF_MU + node * 16 + cj] = cmu[r];
            out[OFF_LV + node * 16 + cj] = clv[r];
            const float z = cmu[r] + eps[node * 16 + cj] * __expf(0.5f * clv[r]);
            sA[actaddr(g * 4 + r, cj)] = z;
        }
    }
    __syncthreads();

    // ---- h3 = relu(z @ W3 + b3): sA(z, K padded to 32) -> sB ----
    {
        short8 zh = {0,0,0,0,0,0,0,0}, zl = {0,0,0,0,0,0,0,0};
        if (lane < 32) {
            float v[8];
            const int row = lane & 15, ko = (lane >> 4) * 8;  // 0 or 8
            *(float4v*)&v[0] = *(const float4v*)&sA[actaddr(row, ko)];
            *(float4v*)&v[4] = *(const float4v*)&sA[actaddr(row, ko + 4)];
            split8(v, zh, zl);
        }
        c = gemm_one<1>(&zh, &zl, gw, SW_W3, wid, 4, bj3, lane);
    }
    write_slab(sB, c, wid, lane);
    __syncthreads();

    // ---- recon = sigmoid(h3 @ W4 + b4): sB -> out ----
    frags_from_act<2>(sB, lane, ah, al);
    c = gemm_one<2>(ah, al, gw, SW_W4, wid, 8, bj4, lane);
    #pragma unroll
    for (int r = 0; r < 4; ++r) {
        const float s = 1.0f / (1.0f + __expf(-c[r]));
        out[(base + g * 4 + r) * 64 + wid * 16 + cj] = s;
    }
}

extern "C" void kernel_launch(void* const* d_in, const int* in_sizes, int n_in,
                              void* d_out, int out_size, void* d_ws, size_t ws_size,
                              hipStream_t stream) {
    const float* x        = (const float*)d_in[0];
    const int*   edge_src = (const int*)  d_in[1];
    const int*   edge_dst = (const int*)  d_in[2];
    const float* eps      = (const float*)d_in[3];
    const float* W_agg    = (const float*)d_in[4];
    const float* b_agg    = (const float*)d_in[5];
    const float* W_fus    = (const float*)d_in[6];
    const float* b_fus    = (const float*)d_in[7];
    const float* W1       = (const float*)d_in[8];
    const float* b1       = (const float*)d_in[9];
    const float* W21      = (const float*)d_in[10];
    const float* b21      = (const float*)d_in[11];
    const float* W22      = (const float*)d_in[12];
    const float* b22      = (const float*)d_in[13];
    const float* W3       = (const float*)d_in[14];
    const float* b3       = (const float*)d_in[15];
    const float* W4       = (const float*)d_in[16];
    const float* b4       = (const float*)d_in[17];
    float* out = (float*)d_out;

    int*   row_start = (int*)d_ws;
    short* gw        = (short*)((char*)d_ws + PW_OFF);

    build_row_start<<<(E_EDGES + 255) / 256, 256, 0, stream>>>(edge_dst, row_start);
    pack_weights<<<7, 512, 0, stream>>>(W_agg, W_fus, W1, W21, W22, W3, W4, gw);
    vae_top<<<NTILES, 256, 0, stream>>>(x, edge_src, eps,
                                        b_agg, b_fus, b1, b21, b22, b3, b4,
                                        gw, row_start, out);
}

// Round 11
// 78.217 us; speedup vs baseline: 1.5118x; 1.1224x over previous
//
#include <hip/hip_runtime.h>
#include <math.h>

#define N_NODES 100000
#define E_EDGES 800000
#define NT 16                 // nodes per MFMA tile
#define NTILES (N_NODES / NT) // 6250 (one block per tile, 4 waves split the jt cols)
#define OFF_MU 6400000L
#define OFF_LV 8000000L

typedef __attribute__((ext_vector_type(8))) short short8;
typedef __attribute__((ext_vector_type(4))) float f32x4;
typedef __attribute__((ext_vector_type(4))) float float4v;

// packed-weight fragment regions (units: shorts; each frag = 64 lanes * 8 = 512)
#define SW_AGG 0
#define SW_FUS 8192
#define SW_W1  24576
#define SW_W2  32768
#define SW_W3  36864
#define SW_W4  40960
#define SW_TOT 49152          // 96 KB of shorts

#define PW_OFF (1 << 20)      // packed weights live at ws + 1 MB

__global__ void build_row_start(const int* __restrict__ edge_dst,
                                int* __restrict__ row_start) {
    int e = blockIdx.x * blockDim.x + threadIdx.x;
    if (e >= E_EDGES) return;
    int d = edge_dst[e];
    int dprev = (e == 0) ? -1 : edge_dst[e - 1];
    for (int n = dprev + 1; n <= d; ++n) row_start[n] = e;
    if (e == E_EDGES - 1) {
        for (int n = d + 1; n <= N_NODES; ++n) row_start[n] = E_EDGES;
    }
}

__device__ __forceinline__ unsigned short f2bf(float f) {
    unsigned u = __float_as_uint(f);
    unsigned r = u + 0x7FFFu + ((u >> 16) & 1u);
    return (unsigned short)(r >> 16);
}
__device__ __forceinline__ float bf2f(unsigned short h) {
    return __uint_as_float(((unsigned)h) << 16);
}
__device__ __forceinline__ void split8(const float* v, short8& hi, short8& lo) {
    #pragma unroll
    for (int i = 0; i < 8; ++i) {
        unsigned short h = f2bf(v[i]);
        hi[i] = (short)h;
        lo[i] = (short)f2bf(v[i] - bf2f(h));
    }
}
// single-value split for producer-side plane writes
__device__ __forceinline__ void split1(float f, short& h, short& l) {
    unsigned short hh = f2bf(f);
    h = (short)hh;
    l = (short)f2bf(f - bf2f(hh));
}

// bf16 plane: [16 rows][64 cols], chunk-XOR swizzled (chunk = 8 shorts = 16B).
// short index for (row, col):
__device__ __forceinline__ int pidx(int row, int col) {
    const int c = ((col >> 3) ^ (row & 7));
    return row * 64 + c * 8 + (col & 7);
}

// pack one weight matrix into hi/lo bf16 B-fragment layout (dst in global ws)
__device__ void stage_w(const float* __restrict__ W, int Ksrc, int NC,
                        int NKT, int NJT_local, int jt_off, int NF_tot,
                        int rb, short* sw, int tid) {
    const int tot = NJT_local * NKT * 64;
    for (int s = tid; s < tot; s += 512) {
        int f = s >> 6, l = s & 63;
        int jtl = f / NKT, kt = f - jtl * NKT;
        int col = jtl * 16 + (l & 15);
        int k0 = kt * 32 + ((l >> 4) << 3);
        float v[8];
        #pragma unroll
        for (int i = 0; i < 8; ++i)
            v[i] = (k0 + i < Ksrc) ? W[(k0 + i) * NC + col] : 0.0f;
        short8 hi, lo; split8(v, hi, lo);
        int fg = (jt_off + jtl) * NKT + kt;
        *(short8*)&sw[rb + fg * 512 + l * 8] = hi;
        *(short8*)&sw[rb + (NF_tot + fg) * 512 + l * 8] = lo;
    }
}

__global__ __launch_bounds__(512) void pack_weights(
    const float* __restrict__ W_agg, const float* __restrict__ W_fus,
    const float* __restrict__ W1,  const float* __restrict__ W21,
    const float* __restrict__ W22, const float* __restrict__ W3,
    const float* __restrict__ W4, short* __restrict__ gw) {
    const int tid = threadIdx.x;
    switch (blockIdx.x) {
        case 0: stage_w(W_agg, 64, 64, 2, 4, 0,  8, SW_AGG, gw, tid); break;
        case 1: stage_w(W_fus, 128, 64, 4, 4, 0, 16, SW_FUS, gw, tid); break;
        case 2: stage_w(W1,   64, 64, 2, 4, 0,  8, SW_W1,  gw, tid); break;
        case 3: stage_w(W21,  64, 16, 2, 1, 0,  4, SW_W2,  gw, tid); break;
        case 4: stage_w(W22,  64, 16, 2, 1, 1,  4, SW_W2,  gw, tid); break;
        case 5: stage_w(W3,   16, 64, 1, 4, 0,  4, SW_W3,  gw, tid); break;
        case 6: stage_w(W4,   64, 64, 2, 4, 0,  8, SW_W4,  gw, tid); break;
    }
}

// build A-frags (kt=0,1) for rows base..base+15 of a row-major [*,64] matrix
__device__ __forceinline__ void frags_from_global(const float* __restrict__ rowmat,
                                                  long base, int lane,
                                                  short8* hi, short8* lo) {
    const int row = lane & 15, ko = (lane >> 4) * 8;
    const float* r = rowmat + (base + row) * 64;
    float v[8];
    *(float4v*)&v[0] = *(const float4v*)&r[ko];
    *(float4v*)&v[4] = *(const float4v*)&r[ko + 4];
    split8(v, hi[0], lo[0]);
    *(float4v*)&v[0] = *(const float4v*)&r[32 + ko];
    *(float4v*)&v[4] = *(const float4v*)&r[32 + ko + 4];
    split8(v, hi[1], lo[1]);
}

// A-frags straight from pre-split bf16 planes: pure ds_read_b128, zero VALU
template<int NKT>
__device__ __forceinline__ void frags_from_planes(const short* phi, const short* plo,
                                                  int lane, short8* hi, short8* lo) {
    const int row = lane & 15;
    #pragma unroll
    for (int kt = 0; kt < NKT; ++kt) {
        const int c = kt * 4 + (lane >> 4);            // chunk of cols kt*32+ko
        const int idx = row * 64 + ((c ^ (row & 7)) << 3);
        hi[kt] = *(const short8*)&phi[idx];
        lo[kt] = *(const short8*)&plo[idx];
    }
}

// one jt-column-slab GEMM (16 rows x 16 cols), B-frags from global packed weights
template<int NKT>
__device__ __forceinline__ f32x4 gemm_one(const short8* ah, const short8* al,
                                          const short* __restrict__ sw, int rb,
                                          int jt, int NF, float bias, int lane) {
    f32x4 acc = { bias, bias, bias, bias };
    #pragma unroll
    for (int kt = 0; kt < NKT; ++kt) {
        const short8 bhi = *(const short8*)&sw[rb + (jt * NKT + kt) * 512 + lane * 8];
        const short8 blo = *(const short8*)&sw[rb + (NF + jt * NKT + kt) * 512 + lane * 8];
        acc = __builtin_amdgcn_mfma_f32_16x16x32_bf16(ah[kt], bhi, acc, 0, 0, 0);
        acc = __builtin_amdgcn_mfma_f32_16x16x32_bf16(al[kt], bhi, acc, 0, 0, 0);
        acc = __builtin_amdgcn_mfma_f32_16x16x32_bf16(ah[kt], blo, acc, 0, 0, 0);
    }
    return acc;
}

// producer-side: relu + split + write into hi/lo planes (4 values/lane)
__device__ __forceinline__ void write_slab_planes(short* phi, short* plo,
                                                  f32x4 c, int jt, int lane,
                                                  bool relu) {
    const int g = lane >> 4, cj = lane & 15;
    const int col = jt * 16 + cj;
    #pragma unroll
    for (int r = 0; r < 4; ++r) {
        float f = relu ? fmaxf(c[r], 0.0f) : c[r];
        short h, l; split1(f, h, l);
        const int idx = pidx(g * 4 + r, col);
        phi[idx] = h;
        plo[idx] = l;
    }
}

__device__ __forceinline__ float tree16(const float* v) {
    float a0 = (v[0] + v[1]) + (v[2] + v[3]);
    float a1 = (v[4] + v[5]) + (v[6] + v[7]);
    float a2 = (v[8] + v[9]) + (v[10] + v[11]);
    float a3 = (v[12] + v[13]) + (v[14] + v[15]);
    return (a0 + a1) + (a2 + a3);
}

// 1 block = 1 tile (16 nodes); 4 waves split the 4 jt column slabs.
// launch_bounds(256,6): ~85 VGPR cap (r9's (256,8)=32 VGPR caused spill).
__global__ __launch_bounds__(256, 6) void vae_top(
    const float* __restrict__ x,
    const int* __restrict__ edge_src,
    const float* __restrict__ eps,
    const float* __restrict__ b_agg, const float* __restrict__ b_fus,
    const float* __restrict__ b1,  const float* __restrict__ b21,
    const float* __restrict__ b22, const float* __restrict__ b3,
    const float* __restrict__ b4,
    const short* __restrict__ gw,
    const int* __restrict__ row_start,
    float* __restrict__ out)
{
    // bf16 activation planes: ping (A) / pong (B), hi/lo each 16x64 shorts = 2KB
    __shared__ __align__(16) short sAhi[1024], sAlo[1024];
    __shared__ __align__(16) short sBhi[1024], sBlo[1024];

    const int tid  = threadIdx.x;
    const int lane = tid & 63;
    const int wid  = tid >> 6;       // wave id == jt slab
    const long base = (long)blockIdx.x * NT;
    const int cj = lane & 15, g = lane >> 4;

    // per-wave biases for own jt slab
    const float bja = b_agg[wid * 16 + cj];
    const float bjf = b_fus[wid * 16 + cj];
    const float bj1 = b1[wid * 16 + cj];
    const float bj3 = b3[wid * 16 + cj];
    const float bj4 = b4[wid * 16 + cj];

    // ---- gather: each wave does 4 nodes (one masked 16-wide batch each) ----
    {
        const int rsv = row_start[(int)base + (lane < 17 ? lane : 16)];
        const int W0 = __builtin_amdgcn_readlane(rsv, wid * 4);
        int p0 = W0 + lane;      p0 = p0 < E_EDGES ? p0 : E_EDGES - 1;
        int p1 = W0 + 64 + lane; p1 = p1 < E_EDGES ? p1 : E_EDGES - 1;
        const int iv0 = edge_src[p0];
        const int iv1 = edge_src[p1];

        #pragma unroll
        for (int q = 0; q < 4; ++q) {
            const int node = wid * 4 + q;
            const int e0 = __builtin_amdgcn_readlane(rsv, node);
            const int e1 = __builtin_amdgcn_readlane(rsv, node + 1);
            float v[16];
            const int te0 = e0 - W0;
            if (te0 + 15 < 128) {
                #pragma unroll
                for (int i = 0; i < 16; ++i) {
                    const int te = te0 + i;
                    const int vsel = (te & 64) ? iv1 : iv0;
                    int ix = __builtin_amdgcn_readlane(vsel, te & 63);
                    const bool live = (e0 + i) < e1;
                    ix = live ? ix : 0;
                    float tv = x[(long)ix * 64 + lane];
                    v[i] = live ? tv : 0.0f;
                }
            } else {
                #pragma unroll
                for (int i = 0; i < 16; ++i) {
                    const int ee = e0 + i;
                    const bool live = ee < e1;
                    const int ec = ee < E_EDGES ? ee : E_EDGES - 1;
                    int ix = edge_src[ec];
                    ix = live ? ix : 0;
                    float tv = x[(long)ix * 64 + lane];
                    v[i] = live ? tv : 0.0f;
                }
            }
            float sum = tree16(v);
            for (int e = e0 + 16; e < e1; ++e)          // rare (deg>16)
                sum += x[(long)edge_src[e] * 64 + lane];
            const float avg = sum / fmaxf((float)(e1 - e0), 1.0f);
            short h, l; split1(avg, h, l);
            const int idx = pidx(node, lane);
            sAhi[idx] = h;
            sAlo[idx] = l;
        }
    }
    __syncthreads();

    short8 ah[4], al[4];
    f32x4 c;

    // ---- ne = relu(avg @ W_agg + b_agg): A -> B ----
    frags_from_planes<2>(sAhi, sAlo, lane, ah, al);
    c = gemm_one<2>(ah, al, gw, SW_AGG, wid, 8, bja, lane);
    write_slab_planes(sBhi, sBlo, c, wid, lane, true);
    __syncthreads();

    // ---- xf = relu([x, ne] @ W_fus + b_fus): x(global) + B -> A ----
    frags_from_global(x, base, lane, ah, al);            // kt 0,1 (x)
    frags_from_planes<2>(sBhi, sBlo, lane, ah + 2, al + 2);  // kt 2,3 (ne)
    c = gemm_one<4>(ah, al, gw, SW_FUS, wid, 16, bjf, lane);
    write_slab_planes(sAhi, sAlo, c, wid, lane, true);
    __syncthreads();

    // ---- h1 = relu(xf @ W1 + b1): A -> B ----
    frags_from_planes<2>(sAhi, sAlo, lane, ah, al);
    c = gemm_one<2>(ah, al, gw, SW_W1, wid, 8, bj1, lane);
    write_slab_planes(sBhi, sBlo, c, wid, lane, true);
    __syncthreads();

    // ---- mu/lv/z (wave 0 only): B -> z into A cols 0..15 ----
    if (wid == 0) {
        frags_from_planes<2>(sBhi, sBlo, lane, ah, al);
        const f32x4 cmu = gemm_one<2>(ah, al, gw, SW_W2, 0, 4, b21[cj], lane);
        const f32x4 clv = gemm_one<2>(ah, al, gw, SW_W2, 1, 4, b22[cj], lane);
        #pragma unroll
        for (int r = 0; r < 4; ++r) {
            const long node = base + g * 4 + r;
            out[OFF_MU + node * 16 + cj] = cmu[r];
            out[OFF_LV + node * 16 + cj] = clv[r];
            const float z = cmu[r] + eps[node * 16 + cj] * __expf(0.5f * clv[r]);
            short h, l; split1(z, h, l);
            const int idx = pidx(g * 4 + r, cj);
            sAhi[idx] = h;
            sAlo[idx] = l;
        }
    }
    __syncthreads();

    // ---- h3 = relu(z @ W3 + b3): A(z, K padded to 32) -> B ----
    {
        short8 zh = {0,0,0,0,0,0,0,0}, zl = {0,0,0,0,0,0,0,0};
        if (lane < 32) {
            const int row = lane & 15;
            const int cch = (lane >> 4);               // chunk 0 or 1 (cols 0..15)
            const int idx = row * 64 + ((cch ^ (row & 7)) << 3);
            zh = *(const short8*)&sAhi[idx];
            zl = *(const short8*)&sAlo[idx];
        }
        c = gemm_one<1>(&zh, &zl, gw, SW_W3, wid, 4, bj3, lane);
    }
    write_slab_planes(sBhi, sBlo, c, wid, lane, true);
    __syncthreads();

    // ---- recon = sigmoid(h3 @ W4 + b4): B -> out ----
    frags_from_planes<2>(sBhi, sBlo, lane, ah, al);
    c = gemm_one<2>(ah, al, gw, SW_W4, wid, 8, bj4, lane);
    #pragma unroll
    for (int r = 0; r < 4; ++r) {
        const float s = 1.0f / (1.0f + __expf(-c[r]));
        out[(base + g * 4 + r) * 64 + wid * 16 + cj] = s;
    }
}

extern "C" void kernel_launch(void* const* d_in, const int* in_sizes, int n_in,
                              void* d_out, int out_size, void* d_ws, size_t ws_size,
                              hipStream_t stream) {
    const float* x        = (const float*)d_in[0];
    const int*   edge_src = (const int*)  d_in[1];
    const int*   edge_dst = (const int*)  d_in[2];
    const float* eps      = (const float*)d_in[3];
    const float* W_agg    = (const float*)d_in[4];
    const float* b_agg    = (const float*)d_in[5];
    const float* W_fus    = (const float*)d_in[6];
    const float* b_fus    = (const float*)d_in[7];
    const float* W1       = (const float*)d_in[8];
    const float* b1       = (const float*)d_in[9];
    const float* W21      = (const float*)d_in[10];
    const float* b21      = (const float*)d_in[11];
    const float* W22      = (const float*)d_in[12];
    const float* b22      = (const float*)d_in[13];
    const float* W3       = (const float*)d_in[14];
    const float* b3       = (const float*)d_in[15];
    const float* W4       = (const float*)d_in[16];
    const float* b4       = (const float*)d_in[17];
    float* out = (float*)d_out;

    int*   row_start = (int*)d_ws;
    short* gw        = (short*)((char*)d_ws + PW_OFF);

    build_row_start<<<(E_EDGES + 255) / 256, 256, 0, stream>>>(edge_dst, row_start);
    pack_weights<<<7, 512, 0, stream>>>(W_agg, W_fus, W1, W21, W22, W3, W4, gw);
    vae_top<<<NTILES, 256, 0, stream>>>(x, edge_src, eps,
                                        b_agg, b_fus, b1, b21, b22, b3, b4,
                                        gw, row_start, out);
}

// Round 12
// 65.312 us; speedup vs baseline: 1.8106x; 1.1976x over previous
//
#include <hip/hip_runtime.h>
#include <math.h>

#define N_NODES 100000
#define E_EDGES 800000
#define NT 16                 // nodes per MFMA tile
#define NTILES (N_NODES / NT) // 6250 (one block per tile, 4 waves split the jt cols)
#define OFF_MU 6400000L
#define OFF_LV 8000000L

typedef __attribute__((ext_vector_type(8))) short short8;
typedef __attribute__((ext_vector_type(4))) float f32x4;
typedef __attribute__((ext_vector_type(4))) float float4v;

// packed-weight fragment regions (units: shorts; each frag = 64 lanes * 8 = 512)
// pure-bf16: single plane per weight
#define SW_AGG 0              // 8 frags  (4 jt x 2 kt)
#define SW_FUS 4096           // 16 frags (4 jt x 4 kt)
#define SW_W1  12288          // 8 frags
#define SW_W2  16384          // 4 frags  (jt0=W21 kt0/1, jt1=W22 kt0/1)
#define SW_W3  18432          // 4 frags  (4 jt x 1 kt, K padded 16->32)
#define SW_W4  20480          // 8 frags
#define SW_TOT 24576          // 48 KB of shorts

#define PW_OFF (1 << 20)      // packed weights at ws + 1 MB
#define XB_OFF (2 << 20)      // bf16 x at ws + 2 MB (12.8 MB)

__global__ void build_row_start(const int* __restrict__ edge_dst,
                                int* __restrict__ row_start) {
    int e = blockIdx.x * blockDim.x + threadIdx.x;
    if (e >= E_EDGES) return;
    int d = edge_dst[e];
    int dprev = (e == 0) ? -1 : edge_dst[e - 1];
    for (int n = dprev + 1; n <= d; ++n) row_start[n] = e;
    if (e == E_EDGES - 1) {
        for (int n = d + 1; n <= N_NODES; ++n) row_start[n] = E_EDGES;
    }
}

__device__ __forceinline__ unsigned short f2bf(float f) {
    unsigned u = __float_as_uint(f);
    unsigned r = u + 0x7FFFu + ((u >> 16) & 1u);
    return (unsigned short)(r >> 16);
}

// bf16 plane: [16 rows][64 cols], chunk-XOR swizzled (chunk = 8 shorts = 16B)
__device__ __forceinline__ int pidx(int row, int col) {
    const int c = ((col >> 3) ^ (row & 7));
    return row * 64 + c * 8 + (col & 7);
}

// pack one weight matrix into bf16 B-fragment layout (dst in global ws)
__device__ void stage_w(const float* __restrict__ W, int Ksrc, int NC,
                        int NKT, int NJT_local, int jt_off,
                        int rb, short* sw, int tid) {
    const int tot = NJT_local * NKT * 64;
    for (int s = tid; s < tot; s += 512) {
        int f = s >> 6, l = s & 63;
        int jtl = f / NKT, kt = f - jtl * NKT;
        int col = jtl * 16 + (l & 15);
        int k0 = kt * 32 + ((l >> 4) << 3);
        short8 hi;
        #pragma unroll
        for (int i = 0; i < 8; ++i) {
            float v = (k0 + i < Ksrc) ? W[(k0 + i) * NC + col] : 0.0f;
            hi[i] = (short)f2bf(v);
        }
        int fg = (jt_off + jtl) * NKT + kt;
        *(short8*)&sw[rb + fg * 512 + l * 8] = hi;
    }
}

__global__ __launch_bounds__(512) void pack_weights(
    const float* __restrict__ W_agg, const float* __restrict__ W_fus,
    const float* __restrict__ W1,  const float* __restrict__ W21,
    const float* __restrict__ W22, const float* __restrict__ W3,
    const float* __restrict__ W4, short* __restrict__ gw) {
    const int tid = threadIdx.x;
    switch (blockIdx.x) {
        case 0: stage_w(W_agg, 64, 64, 2, 4, 0, SW_AGG, gw, tid); break;
        case 1: stage_w(W_fus, 128, 64, 4, 4, 0, SW_FUS, gw, tid); break;
        case 2: stage_w(W1,   64, 64, 2, 4, 0, SW_W1,  gw, tid); break;
        case 3: stage_w(W21,  64, 16, 2, 1, 0, SW_W2,  gw, tid); break;
        case 4: stage_w(W22,  64, 16, 2, 1, 1, SW_W2,  gw, tid); break;
        case 5: stage_w(W3,   16, 64, 1, 4, 0, SW_W3,  gw, tid); break;
        case 6: stage_w(W4,   64, 64, 2, 4, 0, SW_W4,  gw, tid); break;
    }
}

// convert x to bf16 row-major (zero-VALU A-frag loads later)
__global__ __launch_bounds__(256) void pack_x(const float* __restrict__ x,
                                              short* __restrict__ xbf) {
    const int i = blockIdx.x * 256 + threadIdx.x;   // one short8 (8 values) each
    if (i >= N_NODES * 8) return;
    const float4v a = ((const float4v*)x)[i * 2];
    const float4v b = ((const float4v*)x)[i * 2 + 1];
    short8 s;
    s[0] = (short)f2bf(a.x); s[1] = (short)f2bf(a.y);
    s[2] = (short)f2bf(a.z); s[3] = (short)f2bf(a.w);
    s[4] = (short)f2bf(b.x); s[5] = (short)f2bf(b.y);
    s[6] = (short)f2bf(b.z); s[7] = (short)f2bf(b.w);
    ((short8*)xbf)[i] = s;
}

// A-frags (kt=0,1) for rows base..base+15 from prepacked bf16 row-major x
__device__ __forceinline__ void frags_from_xbf(const short* __restrict__ xbf,
                                               long base, int lane, short8* h) {
    const int row = lane & 15, ko = (lane >> 4) * 8;
    const short* r = xbf + (base + row) * 64;
    h[0] = *(const short8*)&r[ko];
    h[1] = *(const short8*)&r[32 + ko];
}

// A-frags from bf16 LDS plane: pure ds_read_b128
template<int NKT>
__device__ __forceinline__ void frags_from_planes(const short* phi, int lane,
                                                  short8* hi) {
    const int row = lane & 15;
    #pragma unroll
    for (int kt = 0; kt < NKT; ++kt) {
        const int c = kt * 4 + (lane >> 4);
        const int idx = row * 64 + ((c ^ (row & 7)) << 3);
        hi[kt] = *(const short8*)&phi[idx];
    }
}

// one jt-column-slab GEMM (16 rows x 16 cols), bf16 B from global packed weights
template<int NKT>
__device__ __forceinline__ f32x4 gemm_one(const short8* ah,
                                          const short* __restrict__ sw, int rb,
                                          int jt, float bias, int lane) {
    f32x4 acc = { bias, bias, bias, bias };
    #pragma unroll
    for (int kt = 0; kt < NKT; ++kt) {
        const short8 bhi = *(const short8*)&sw[rb + (jt * NKT + kt) * 512 + lane * 8];
        acc = __builtin_amdgcn_mfma_f32_16x16x32_bf16(ah[kt], bhi, acc, 0, 0, 0);
    }
    return acc;
}

// producer-side: relu + bf16 round + write into plane (4 values/lane)
__device__ __forceinline__ void write_slab_plane(short* phi, f32x4 c, int jt,
                                                 int lane, bool relu) {
    const int g = lane >> 4, cj = lane & 15;
    const int col = jt * 16 + cj;
    #pragma unroll
    for (int r = 0; r < 4; ++r) {
        float f = relu ? fmaxf(c[r], 0.0f) : c[r];
        phi[pidx(g * 4 + r, col)] = (short)f2bf(f);
    }
}

__device__ __forceinline__ float tree16(const float* v) {
    float a0 = (v[0] + v[1]) + (v[2] + v[3]);
    float a1 = (v[4] + v[5]) + (v[6] + v[7]);
    float a2 = (v[8] + v[9]) + (v[10] + v[11]);
    float a3 = (v[12] + v[13]) + (v[14] + v[15]);
    return (a0 + a1) + (a2 + a3);
}
__device__ __forceinline__ float tree8(const float* v) {
    return ((v[0] + v[1]) + (v[2] + v[3])) + ((v[4] + v[5]) + (v[6] + v[7]));
}

// 1 block = 1 tile (16 nodes); 4 waves split the 4 jt column slabs.
__global__ __launch_bounds__(256, 6) void vae_top(
    const float* __restrict__ x,
    const short* __restrict__ xbf,
    const int* __restrict__ edge_src,
    const float* __restrict__ eps,
    const float* __restrict__ b_agg, const float* __restrict__ b_fus,
    const float* __restrict__ b1,  const float* __restrict__ b21,
    const float* __restrict__ b22, const float* __restrict__ b3,
    const float* __restrict__ b4,
    const short* __restrict__ gw,
    const int* __restrict__ row_start,
    float* __restrict__ out)
{
    __shared__ __align__(16) short sA[1024];   // bf16 act plane (ping), 2 KB
    __shared__ __align__(16) short sB[1024];   // (pong)

    const int tid  = threadIdx.x;
    const int lane = tid & 63;
    const int wid  = tid >> 6;       // wave id == jt slab
    const long base = (long)blockIdx.x * NT;
    const int cj = lane & 15, g = lane >> 4;

    const float bja = b_agg[wid * 16 + cj];
    const float bjf = b_fus[wid * 16 + cj];
    const float bj1 = b1[wid * 16 + cj];
    const float bj3 = b3[wid * 16 + cj];
    const float bj4 = b4[wid * 16 + cj];

    // ---- gather: each wave does 4 nodes; deg-adaptive masked batch ----
    {
        const int rsv = row_start[(int)base + (lane < 17 ? lane : 16)];
        const int W0 = __builtin_amdgcn_readlane(rsv, wid * 4);
        int p0 = W0 + lane;      p0 = p0 < E_EDGES ? p0 : E_EDGES - 1;
        int p1 = W0 + 64 + lane; p1 = p1 < E_EDGES ? p1 : E_EDGES - 1;
        const int iv0 = edge_src[p0];
        const int iv1 = edge_src[p1];

        #pragma unroll
        for (int q = 0; q < 4; ++q) {
            const int node = wid * 4 + q;
            const int e0 = __builtin_amdgcn_readlane(rsv, node);
            const int e1 = __builtin_amdgcn_readlane(rsv, node + 1);
            const int deg = e1 - e0;
            const int te0 = e0 - W0;
            float sum;
            if (deg <= 8 && te0 + 7 < 128) {
                float v[8];
                #pragma unroll
                for (int i = 0; i < 8; ++i) {
                    const int te = te0 + i;
                    const int vsel = (te & 64) ? iv1 : iv0;
                    int ix = __builtin_amdgcn_readlane(vsel, te & 63);
                    const bool live = i < deg;
                    ix = live ? ix : 0;
                    float tv = x[(long)ix * 64 + lane];
                    v[i] = live ? tv : 0.0f;
                }
                sum = tree8(v);
            } else if (te0 + 15 < 128) {
                float v[16];
                #pragma unroll
                for (int i = 0; i < 16; ++i) {
                    const int te = te0 + i;
                    const int vsel = (te & 64) ? iv1 : iv0;
                    int ix = __builtin_amdgcn_readlane(vsel, te & 63);
                    const bool live = i < deg;
                    ix = live ? ix : 0;
                    float tv = x[(long)ix * 64 + lane];
                    v[i] = live ? tv : 0.0f;
                }
                sum = tree16(v);
                for (int e = e0 + 16; e < e1; ++e)          // rare (deg>16)
                    sum += x[(long)edge_src[e] * 64 + lane];
            } else {
                float v[16];
                #pragma unroll
                for (int i = 0; i < 16; ++i) {
                    const int ee = e0 + i;
                    const bool live = ee < e1;
                    const int ec = ee < E_EDGES ? ee : E_EDGES - 1;
                    int ix = edge_src[ec];
                    ix = live ? ix : 0;
                    float tv = x[(long)ix * 64 + lane];
                    v[i] = live ? tv : 0.0f;
                }
                sum = tree16(v);
                for (int e = e0 + 16; e < e1; ++e)
                    sum += x[(long)edge_src[e] * 64 + lane];
            }
            const float avg = sum / fmaxf((float)deg, 1.0f);
            sA[pidx(node, lane)] = (short)f2bf(avg);
        }
    }
    __syncthreads();

    short8 ah[4];
    f32x4 c;

    // ---- ne = relu(avg @ W_agg + b_agg): A -> B ----
    frags_from_planes<2>(sA, lane, ah);
    c = gemm_one<2>(ah, gw, SW_AGG, wid, bja, lane);
    write_slab_plane(sB, c, wid, lane, true);
    __syncthreads();

    // ---- xf = relu([x, ne] @ W_fus + b_fus): xbf(global) + B -> A ----
    frags_from_xbf(xbf, base, lane, ah);                 // kt 0,1 (x)
    frags_from_planes<2>(sB, lane, ah + 2);              // kt 2,3 (ne)
    c = gemm_one<4>(ah, gw, SW_FUS, wid, bjf, lane);
    write_slab_plane(sA, c, wid, lane, true);
    __syncthreads();

    // ---- h1 = relu(xf @ W1 + b1): A -> B ----
    frags_from_planes<2>(sA, lane, ah);
    c = gemm_one<2>(ah, gw, SW_W1, wid, bj1, lane);
    write_slab_plane(sB, c, wid, lane, true);
    __syncthreads();

    // ---- mu/lv/z (wave 0 only): B -> z into A cols 0..15 ----
    if (wid == 0) {
        frags_from_planes<2>(sB, lane, ah);
        const f32x4 cmu = gemm_one<2>(ah, gw, SW_W2, 0, b21[cj], lane);
        const f32x4 clv = gemm_one<2>(ah, gw, SW_W2, 1, b22[cj], lane);
        #pragma unroll
        for (int r = 0; r < 4; ++r) {
            const long node = base + g * 4 + r;
            out[OFF_MU + node * 16 + cj] = cmu[r];
            out[OFF_LV + node * 16 + cj] = clv[r];
            const float z = cmu[r] + eps[node * 16 + cj] * __expf(0.5f * clv[r]);
            sA[pidx(g * 4 + r, cj)] = (short)f2bf(z);
        }
    }
    __syncthreads();

    // ---- h3 = relu(z @ W3 + b3): A(z, K padded to 32) -> B ----
    {
        short8 zh = {0,0,0,0,0,0,0,0};
        if (lane < 32) {
            const int row = lane & 15;
            const int cch = (lane >> 4);               // chunk 0 or 1 (cols 0..15)
            zh = *(const short8*)&sA[row * 64 + ((cch ^ (row & 7)) << 3)];
        }
        c = gemm_one<1>(&zh, gw, SW_W3, wid, bj3, lane);
    }
    write_slab_plane(sB, c, wid, lane, true);
    __syncthreads();

    // ---- recon = sigmoid(h3 @ W4 + b4): B -> out ----
    frags_from_planes<2>(sB, lane, ah);
    c = gemm_one<2>(ah, gw, SW_W4, wid, bj4, lane);
    #pragma unroll
    for (int r = 0; r < 4; ++r) {
        const float s = 1.0f / (1.0f + __expf(-c[r]));
        out[(base + g * 4 + r) * 64 + wid * 16 + cj] = s;
    }
}

extern "C" void kernel_launch(void* const* d_in, const int* in_sizes, int n_in,
                              void* d_out, int out_size, void* d_ws, size_t ws_size,
                              hipStream_t stream) {
    const float* x        = (const float*)d_in[0];
    const int*   edge_src = (const int*)  d_in[1];
    const int*   edge_dst = (const int*)  d_in[2];
    const float* eps      = (const float*)d_in[3];
    const float* W_agg    = (const float*)d_in[4];
    const float* b_agg    = (const float*)d_in[5];
    const float* W_fus    = (const float*)d_in[6];
    const float* b_fus    = (const float*)d_in[7];
    const float* W1       = (const float*)d_in[8];
    const float* b1       = (const float*)d_in[9];
    const float* W21      = (const float*)d_in[10];
    const float* b21      = (const float*)d_in[11];
    const float* W22      = (const float*)d_in[12];
    const float* b22      = (const float*)d_in[13];
    const float* W3       = (const float*)d_in[14];
    const float* b3       = (const float*)d_in[15];
    const float* W4       = (const float*)d_in[16];
    const float* b4       = (const float*)d_in[17];
    float* out = (float*)d_out;

    // ws: row_start @0 (400KB) | packed weights @1MB (48KB) | bf16 x @2MB (12.8MB)
    int*   row_start = (int*)d_ws;
    short* gw        = (short*)((char*)d_ws + PW_OFF);
    short* xbf       = (short*)((char*)d_ws + XB_OFF);

    build_row_start<<<(E_EDGES + 255) / 256, 256, 0, stream>>>(edge_dst, row_start);
    pack_weights<<<7, 512, 0, stream>>>(W_agg, W_fus, W1, W21, W22, W3, W4, gw);
    pack_x<<<(N_NODES * 8 + 255) / 256, 256, 0, stream>>>(x, xbf);
    vae_top<<<NTILES, 256, 0, stream>>>(x, xbf, edge_src, eps,
                                        b_agg, b_fus, b1, b21, b22, b3, b4,
                                        gw, row_start, out);
}

// Round 13
// 63.025 us; speedup vs baseline: 1.8763x; 1.0363x over previous
//
#include <hip/hip_runtime.h>
#include <math.h>

#define N_NODES 100000
#define E_EDGES 800000
#define NT 16                 // nodes per MFMA tile
#define NTILES (N_NODES / NT) // 6250 (one block per tile, 4 waves split the jt cols)
#define OFF_MU 6400000L
#define OFF_LV 8000000L

typedef __attribute__((ext_vector_type(8))) short short8;
typedef __attribute__((ext_vector_type(4))) float f32x4;
typedef __attribute__((ext_vector_type(4))) float float4v;

// packed-weight fragment regions (units: shorts; each frag = 64 lanes * 8 = 512)
#define SW_AGG 0              // 8 frags  (4 jt x 2 kt)
#define SW_FUS 4096           // 16 frags (4 jt x 4 kt)
#define SW_W1  12288          // 8 frags
#define SW_W2  16384          // 4 frags  (jt0=W21 kt0/1, jt1=W22 kt0/1)
#define SW_W3  18432          // 4 frags  (4 jt x 1 kt, K padded 16->32)
#define SW_W4  20480          // 8 frags
#define SW_TOT 24576          // 48 KB of shorts

#define PW_OFF (1 << 20)      // packed weights at ws + 1 MB
#define XB_OFF (2 << 20)      // bf16 x at ws + 2 MB (12.8 MB)

// prep grid partition
#define PB_RS 3125            // build_row_start blocks (3125*256 = 800000)
#define PB_W  7               // pack_weights blocks
#define PB_X  3125            // pack_x blocks (100000*8 / 256)

__device__ __forceinline__ unsigned short f2bf(float f) {
    unsigned u = __float_as_uint(f);
    unsigned r = u + 0x7FFFu + ((u >> 16) & 1u);
    return (unsigned short)(r >> 16);
}

// bf16 plane: [16 rows][64 cols], chunk-XOR swizzled (chunk = 8 shorts = 16B)
__device__ __forceinline__ int pidx(int row, int col) {
    const int c = ((col >> 3) ^ (row & 7));
    return row * 64 + c * 8 + (col & 7);
}

// pack one weight matrix into bf16 B-fragment layout (dst in global ws)
__device__ void stage_w(const float* __restrict__ W, int Ksrc, int NC,
                        int NKT, int NJT_local, int jt_off,
                        int rb, short* sw, int tid) {
    const int tot = NJT_local * NKT * 64;
    for (int s = tid; s < tot; s += 256) {
        int f = s >> 6, l = s & 63;
        int jtl = f / NKT, kt = f - jtl * NKT;
        int col = jtl * 16 + (l & 15);
        int k0 = kt * 32 + ((l >> 4) << 3);
        short8 hi;
        #pragma unroll
        for (int i = 0; i < 8; ++i) {
            float v = (k0 + i < Ksrc) ? W[(k0 + i) * NC + col] : 0.0f;
            hi[i] = (short)f2bf(v);
        }
        int fg = (jt_off + jtl) * NKT + kt;
        *(short8*)&sw[rb + fg * 512 + l * 8] = hi;
    }
}

// merged prep: [0,PB_RS) row_start | [PB_RS,+7) weights | rest pack_x
__global__ __launch_bounds__(256) void prep(
    const int* __restrict__ edge_dst, int* __restrict__ row_start,
    const float* __restrict__ W_agg, const float* __restrict__ W_fus,
    const float* __restrict__ W1,  const float* __restrict__ W21,
    const float* __restrict__ W22, const float* __restrict__ W3,
    const float* __restrict__ W4, short* __restrict__ gw,
    const float* __restrict__ x, short* __restrict__ xbf)
{
    const int b = blockIdx.x;
    const int tid = threadIdx.x;
    if (b < PB_RS) {
        const int e = b * 256 + tid;
        if (e >= E_EDGES) return;
        int d = edge_dst[e];
        int dprev = (e == 0) ? -1 : edge_dst[e - 1];
        for (int n = dprev + 1; n <= d; ++n) row_start[n] = e;
        if (e == E_EDGES - 1) {
            for (int n = d + 1; n <= N_NODES; ++n) row_start[n] = E_EDGES;
        }
    } else if (b < PB_RS + PB_W) {
        switch (b - PB_RS) {
            case 0: stage_w(W_agg, 64, 64, 2, 4, 0, SW_AGG, gw, tid); break;
            case 1: stage_w(W_fus, 128, 64, 4, 4, 0, SW_FUS, gw, tid); break;
            case 2: stage_w(W1,   64, 64, 2, 4, 0, SW_W1,  gw, tid); break;
            case 3: stage_w(W21,  64, 16, 2, 1, 0, SW_W2,  gw, tid); break;
            case 4: stage_w(W22,  64, 16, 2, 1, 1, SW_W2,  gw, tid); break;
            case 5: stage_w(W3,   16, 64, 1, 4, 0, SW_W3,  gw, tid); break;
            case 6: stage_w(W4,   64, 64, 2, 4, 0, SW_W4,  gw, tid); break;
        }
    } else {
        const int i = (b - PB_RS - PB_W) * 256 + tid;   // one short8 each
        if (i >= N_NODES * 8) return;
        const float4v a = ((const float4v*)x)[i * 2];
        const float4v c = ((const float4v*)x)[i * 2 + 1];
        short8 s;
        s[0] = (short)f2bf(a.x); s[1] = (short)f2bf(a.y);
        s[2] = (short)f2bf(a.z); s[3] = (short)f2bf(a.w);
        s[4] = (short)f2bf(c.x); s[5] = (short)f2bf(c.y);
        s[6] = (short)f2bf(c.z); s[7] = (short)f2bf(c.w);
        ((short8*)xbf)[i] = s;
    }
}

// A-frags (kt=0,1) for rows base..base+15 from prepacked bf16 row-major x
__device__ __forceinline__ void frags_from_xbf(const short* __restrict__ xbf,
                                               long base, int lane, short8* h) {
    const int row = lane & 15, ko = (lane >> 4) * 8;
    const short* r = xbf + (base + row) * 64;
    h[0] = *(const short8*)&r[ko];
    h[1] = *(const short8*)&r[32 + ko];
}

// A-frags from bf16 LDS plane: pure ds_read_b128
template<int NKT>
__device__ __forceinline__ void frags_from_planes(const short* phi, int lane,
                                                  short8* hi) {
    const int row = lane & 15;
    #pragma unroll
    for (int kt = 0; kt < NKT; ++kt) {
        const int c = kt * 4 + (lane >> 4);
        const int idx = row * 64 + ((c ^ (row & 7)) << 3);
        hi[kt] = *(const short8*)&phi[idx];
    }
}

// one jt-column-slab GEMM (16 rows x 16 cols), bf16 B from global packed weights
template<int NKT>
__device__ __forceinline__ f32x4 gemm_one(const short8* ah,
                                          const short* __restrict__ sw, int rb,
                                          int jt, float bias, int lane) {
    f32x4 acc = { bias, bias, bias, bias };
    #pragma unroll
    for (int kt = 0; kt < NKT; ++kt) {
        const short8 bhi = *(const short8*)&sw[rb + (jt * NKT + kt) * 512 + lane * 8];
        acc = __builtin_amdgcn_mfma_f32_16x16x32_bf16(ah[kt], bhi, acc, 0, 0, 0);
    }
    return acc;
}

// producer-side: relu + bf16 round + write into plane (4 values/lane)
__device__ __forceinline__ void write_slab_plane(short* phi, f32x4 c, int jt,
                                                 int lane, bool relu) {
    const int g = lane >> 4, cj = lane & 15;
    const int col = jt * 16 + cj;
    #pragma unroll
    for (int r = 0; r < 4; ++r) {
        float f = relu ? fmaxf(c[r], 0.0f) : c[r];
        phi[pidx(g * 4 + r, col)] = (short)f2bf(f);
    }
}

__device__ __forceinline__ float tree16(const float* v) {
    float a0 = (v[0] + v[1]) + (v[2] + v[3]);
    float a1 = (v[4] + v[5]) + (v[6] + v[7]);
    float a2 = (v[8] + v[9]) + (v[10] + v[11]);
    float a3 = (v[12] + v[13]) + (v[14] + v[15]);
    return (a0 + a1) + (a2 + a3);
}
__device__ __forceinline__ float tree8(const float* v) {
    return ((v[0] + v[1]) + (v[2] + v[3])) + ((v[4] + v[5]) + (v[6] + v[7]));
}

// 1 block = 1 tile (16 nodes); 4 waves split the 4 jt column slabs.
// (256,8): VGPR cap 64 — kernel uses 36 (r12 measured), no spill; 32 waves/CU.
__global__ __launch_bounds__(256, 8) void vae_top(
    const float* __restrict__ x,
    const short* __restrict__ xbf,
    const int* __restrict__ edge_src,
    const float* __restrict__ eps,
    const float* __restrict__ b_agg, const float* __restrict__ b_fus,
    const float* __restrict__ b1,  const float* __restrict__ b21,
    const float* __restrict__ b22, const float* __restrict__ b3,
    const float* __restrict__ b4,
    const short* __restrict__ gw,
    const int* __restrict__ row_start,
    float* __restrict__ out)
{
    __shared__ __align__(16) short sA[1024];   // bf16 act plane (ping), 2 KB
    __shared__ __align__(16) short sB[1024];   // (pong)

    const int tid  = threadIdx.x;
    const int lane = tid & 63;
    const int wid  = tid >> 6;       // wave id == jt slab
    const long base = (long)blockIdx.x * NT;
    const int cj = lane & 15, g = lane >> 4;

    const float bja = b_agg[wid * 16 + cj];
    const float bjf = b_fus[wid * 16 + cj];
    const float bj1 = b1[wid * 16 + cj];
    const float bj3 = b3[wid * 16 + cj];
    const float bj4 = b4[wid * 16 + cj];

    // ---- gather: each wave does 4 nodes; deg-adaptive masked batch ----
    {
        const int rsv = row_start[(int)base + (lane < 17 ? lane : 16)];
        const int W0 = __builtin_amdgcn_readlane(rsv, wid * 4);
        int p0 = W0 + lane;      p0 = p0 < E_EDGES ? p0 : E_EDGES - 1;
        int p1 = W0 + 64 + lane; p1 = p1 < E_EDGES ? p1 : E_EDGES - 1;
        const int iv0 = edge_src[p0];
        const int iv1 = edge_src[p1];

        #pragma unroll
        for (int q = 0; q < 4; ++q) {
            const int node = wid * 4 + q;
            const int e0 = __builtin_amdgcn_readlane(rsv, node);
            const int e1 = __builtin_amdgcn_readlane(rsv, node + 1);
            const int deg = e1 - e0;
            const int te0 = e0 - W0;
            float sum;
            if (deg <= 8 && te0 + 7 < 128) {
                float v[8];
                #pragma unroll
                for (int i = 0; i < 8; ++i) {
                    const int te = te0 + i;
                    const int vsel = (te & 64) ? iv1 : iv0;
                    int ix = __builtin_amdgcn_readlane(vsel, te & 63);
                    const bool live = i < deg;
                    ix = live ? ix : 0;
                    float tv = x[(long)ix * 64 + lane];
                    v[i] = live ? tv : 0.0f;
                }
                sum = tree8(v);
            } else if (te0 + 15 < 128) {
                float v[16];
                #pragma unroll
                for (int i = 0; i < 16; ++i) {
                    const int te = te0 + i;
                    const int vsel = (te & 64) ? iv1 : iv0;
                    int ix = __builtin_amdgcn_readlane(vsel, te & 63);
                    const bool live = i < deg;
                    ix = live ? ix : 0;
                    float tv = x[(long)ix * 64 + lane];
                    v[i] = live ? tv : 0.0f;
                }
                sum = tree16(v);
                for (int e = e0 + 16; e < e1; ++e)          // rare (deg>16)
                    sum += x[(long)edge_src[e] * 64 + lane];
            } else {
                float v[16];
                #pragma unroll
                for (int i = 0; i < 16; ++i) {
                    const int ee = e0 + i;
                    const bool live = ee < e1;
                    const int ec = ee < E_EDGES ? ee : E_EDGES - 1;
                    int ix = edge_src[ec];
                    ix = live ? ix : 0;
                    float tv = x[(long)ix * 64 + lane];
                    v[i] = live ? tv : 0.0f;
                }
                sum = tree16(v);
                for (int e = e0 + 16; e < e1; ++e)
                    sum += x[(long)edge_src[e] * 64 + lane];
            }
            const float avg = sum / fmaxf((float)deg, 1.0f);
            sA[pidx(node, lane)] = (short)f2bf(avg);
        }
    }
    __syncthreads();

    short8 ah[4];
    f32x4 c;

    // ---- ne = relu(avg @ W_agg + b_agg): A -> B ----
    frags_from_planes<2>(sA, lane, ah);
    c = gemm_one<2>(ah, gw, SW_AGG, wid, bja, lane);
    write_slab_plane(sB, c, wid, lane, true);
    __syncthreads();

    // ---- xf = relu([x, ne] @ W_fus + b_fus): xbf(global) + B -> A ----
    frags_from_xbf(xbf, base, lane, ah);                 // kt 0,1 (x)
    frags_from_planes<2>(sB, lane, ah + 2);              // kt 2,3 (ne)
    c = gemm_one<4>(ah, gw, SW_FUS, wid, bjf, lane);
    write_slab_plane(sA, c, wid, lane, true);
    __syncthreads();

    // ---- h1 = relu(xf @ W1 + b1): A -> B ----
    frags_from_planes<2>(sA, lane, ah);
    c = gemm_one<2>(ah, gw, SW_W1, wid, bj1, lane);
    write_slab_plane(sB, c, wid, lane, true);
    __syncthreads();

    // ---- mu/lv/z (wave 0 only): B -> z into A cols 0..15 ----
    if (wid == 0) {
        frags_from_planes<2>(sB, lane, ah);
        const f32x4 cmu = gemm_one<2>(ah, gw, SW_W2, 0, b21[cj], lane);
        const f32x4 clv = gemm_one<2>(ah, gw, SW_W2, 1, b22[cj], lane);
        #pragma unroll
        for (int r = 0; r < 4; ++r) {
            const long node = base + g * 4 + r;
            out[OFF_MU + node * 16 + cj] = cmu[r];
            out[OFF_LV + node * 16 + cj] = clv[r];
            const float z = cmu[r] + eps[node * 16 + cj] * __expf(0.5f * clv[r]);
            sA[pidx(g * 4 + r, cj)] = (short)f2bf(z);
        }
    }
    __syncthreads();

    // ---- h3 = relu(z @ W3 + b3): A(z, K padded to 32) -> B ----
    {
        short8 zh = {0,0,0,0,0,0,0,0};
        if (lane < 32) {
            const int row = lane & 15;
            const int cch = (lane >> 4);               // chunk 0 or 1 (cols 0..15)
            zh = *(const short8*)&sA[row * 64 + ((cch ^ (row & 7)) << 3)];
        }
        c = gemm_one<1>(&zh, gw, SW_W3, wid, bj3, lane);
    }
    write_slab_plane(sB, c, wid, lane, true);
    __syncthreads();

    // ---- recon = sigmoid(h3 @ W4 + b4): B -> out ----
    frags_from_planes<2>(sB, lane, ah);
    c = gemm_one<2>(ah, gw, SW_W4, wid, bj4, lane);
    #pragma unroll
    for (int r = 0; r < 4; ++r) {
        const float s = 1.0f / (1.0f + __expf(-c[r]));
        out[(base + g * 4 + r) * 64 + wid * 16 + cj] = s;
    }
}

extern "C" void kernel_launch(void* const* d_in, const int* in_sizes, int n_in,
                              void* d_out, int out_size, void* d_ws, size_t ws_size,
                              hipStream_t stream) {
    const float* x        = (const float*)d_in[0];
    const int*   edge_src = (const int*)  d_in[1];
    const int*   edge_dst = (const int*)  d_in[2];
    const float* eps      = (const float*)d_in[3];
    const float* W_agg    = (const float*)d_in[4];
    const float* b_agg    = (const float*)d_in[5];
    const float* W_fus    = (const float*)d_in[6];
    const float* b_fus    = (const float*)d_in[7];
    const float* W1       = (const float*)d_in[8];
    const float* b1       = (const float*)d_in[9];
    const float* W21      = (const float*)d_in[10];
    const float* b21      = (const float*)d_in[11];
    const float* W22      = (const float*)d_in[12];
    const float* b22      = (const float*)d_in[13];
    const float* W3       = (const float*)d_in[14];
    const float* b3       = (const float*)d_in[15];
    const float* W4       = (const float*)d_in[16];
    const float* b4       = (const float*)d_in[17];
    float* out = (float*)d_out;

    // ws: row_start @0 (400KB) | packed weights @1MB (48KB) | bf16 x @2MB (12.8MB)
    int*   row_start = (int*)d_ws;
    short* gw        = (short*)((char*)d_ws + PW_OFF);
    short* xbf       = (short*)((char*)d_ws + XB_OFF);

    prep<<<PB_RS + PB_W + PB_X, 256, 0, stream>>>(edge_dst, row_start,
                                                  W_agg, W_fus, W1, W21, W22, W3, W4,
                                                  gw, x, xbf);
    vae_top<<<NTILES, 256, 0, stream>>>(x, xbf, edge_src, eps,
                                        b_agg, b_fus, b1, b21, b22, b3, b4,
                                        gw, row_start, out);
}